// Round 1
// baseline (340.889 us; speedup 1.0000x reference)
//
#include <hip/hip_runtime.h>
#include <cstdint>
#include <cstddef>

typedef __attribute__((ext_vector_type(8))) short bf16x8;
typedef __attribute__((ext_vector_type(4))) float f32x4;
typedef unsigned short ushort_t;

#define MFMA_BF16(a, b, c) __builtin_amdgcn_mfma_f32_16x16x32_bf16((a), (b), (c), 0, 0, 0)

__device__ __forceinline__ unsigned short f2bf(float f) {
  unsigned int u = __float_as_uint(f);
  u += 0x7fffu + ((u >> 16) & 1u);           // round-to-nearest-even
  return (unsigned short)(u >> 16);
}
__device__ __forceinline__ float bf2f(unsigned short h) {
  return __uint_as_float(((unsigned int)h) << 16);
}

__device__ __forceinline__ void gload_lds16(const void* g, void* lds) {
  __builtin_amdgcn_global_load_lds(
      (const __attribute__((address_space(1))) void*)g,
      (__attribute__((address_space(3))) void*)lds, 16, 0, 0);
}

// ---------------------------------------------------------------- convert
__global__ __launch_bounds__(256)
void cvt_kernel(const float* __restrict__ x, const float* __restrict__ wq,
                const float* __restrict__ wk, const float* __restrict__ wv,
                const float* __restrict__ wo,
                ushort_t* __restrict__ xb, ushort_t* __restrict__ wqb,
                ushort_t* __restrict__ wkb, ushort_t* __restrict__ wvb,
                ushort_t* __restrict__ wob) {
  const float* src; ushort_t* dst; int n;
  switch (blockIdx.y) {
    case 0:  src = x;  dst = xb;  n = 8388608; break;
    case 1:  src = wq; dst = wqb; n = 4194304; break;
    case 2:  src = wk; dst = wkb; n = 1048576; break;
    case 3:  src = wv; dst = wvb; n = 1048576; break;
    default: src = wo; dst = wob; n = 4194304; break;
  }
  const int i = (int)(blockIdx.x * 256u + threadIdx.x) * 4;
  if (i >= n) return;
  const float4 v = *(const float4*)(src + i);
  union { unsigned short us[4]; unsigned long long u64; } pk;
  pk.us[0] = f2bf(v.x); pk.us[1] = f2bf(v.y);
  pk.us[2] = f2bf(v.z); pk.us[3] = f2bf(v.w);
  *(unsigned long long*)(dst + i) = pk.u64;
}

// ---------------------------------------------------------------- GEMM  C = A * B^T
// A: M x K bf16 row-major, B: N x K bf16 row-major.
// WMODE 0: bf16 C row-major; 1: f32 C row-major; 2: bf16 C transposed per batch
// (for V^T: out[b][n][t] with b = m>>11, t = m&2047, n-stride 2048).
// Tiles: BM=BN=128, BK=64. 4 waves; wave w -> 64x64 quadrant (wr=w>>1, wc=w&1).
// LDS [128][64] bf16 per operand, row=128B=8 16B-groups, XOR-swizzle group^=(row&7)
// applied via pre-swizzled global source (linear global_load_lds dest, rule #21).
template<int WMODE>
__global__ __launch_bounds__(256, 2)
void gemm_bt(const ushort_t* __restrict__ A, const ushort_t* __restrict__ B,
             void* __restrict__ Cout, int M, int N, int K) {
  __shared__ bf16x8 smem[2048];              // 32 KB
  char* As = (char*)smem;                    // 16 KB
  char* Bs = (char*)smem + 16384;            // 16 KB
  const int tid  = threadIdx.x;
  const int lane = tid & 63;
  const int wave = tid >> 6;
  const int wr = wave >> 1, wc = wave & 1;
  const ushort_t* Abase = A + (size_t)blockIdx.x * 128 * K;
  const ushort_t* Bbase = B + (size_t)blockIdx.y * 128 * K;

  f32x4 acc[4][4] = {};

  for (int k0 = 0; k0 < K; k0 += 64) {
    #pragma unroll
    for (int it = 0; it < 4; ++it) {
      const int chunk = it * 4 + wave;       // 16 chunks of 1 KB per operand
      const int r  = chunk * 8 + (lane >> 3);
      const int cg = (lane & 7) ^ (r & 7);   // inverse-swizzled source group
      gload_lds16(Abase + (size_t)r * K + k0 + cg * 8, As + chunk * 1024);
      gload_lds16(Bbase + (size_t)r * K + k0 + cg * 8, Bs + chunk * 1024);
    }
    __syncthreads();

    bf16x8 af[2][4], bf_[2][4];
    #pragma unroll
    for (int kki = 0; kki < 2; ++kki) {
      #pragma unroll
      for (int m = 0; m < 4; ++m) {
        const int row = wr * 64 + m * 16 + (lane & 15);
        const int cg  = ((kki << 2) + (lane >> 4)) ^ (row & 7);
        af[kki][m] = *(const bf16x8*)(As + row * 128 + cg * 16);
      }
      #pragma unroll
      for (int n = 0; n < 4; ++n) {
        const int row = wc * 64 + n * 16 + (lane & 15);
        const int cg  = ((kki << 2) + (lane >> 4)) ^ (row & 7);
        bf_[kki][n] = *(const bf16x8*)(Bs + row * 128 + cg * 16);
      }
    }
    #pragma unroll
    for (int kki = 0; kki < 2; ++kki)
      #pragma unroll
      for (int m = 0; m < 4; ++m)
        #pragma unroll
        for (int n = 0; n < 4; ++n)
          acc[m][n] = MFMA_BF16(af[kki][m], bf_[kki][n], acc[m][n]);
    __syncthreads();
  }

  const int row0 = blockIdx.x * 128 + wr * 64;
  const int col0 = blockIdx.y * 128 + wc * 64;
  #pragma unroll
  for (int m = 0; m < 4; ++m) {
    #pragma unroll
    for (int n = 0; n < 4; ++n) {
      #pragma unroll
      for (int j = 0; j < 4; ++j) {
        // C/D layout: col = lane&15, row = (lane>>4)*4 + j   [m89/m91 verified]
        const int gm = row0 + m * 16 + ((lane >> 4) << 2) + j;
        const int gn = col0 + n * 16 + (lane & 15);
        const float v = acc[m][n][j];
        if (WMODE == 0) {
          ((ushort_t*)Cout)[(size_t)gm * N + gn] = f2bf(v);
        } else if (WMODE == 1) {
          ((float*)Cout)[(size_t)gm * N + gn] = v;
        } else {
          const int bb = gm >> 11, t = gm & 2047;
          ((ushort_t*)Cout)[(size_t)bb * N * 2048 + (size_t)gn * 2048 + t] = f2bf(v);
        }
      }
    }
  }
}

// ---------------------------------------------------------------- RoPE (head-indexed!)
// Reference bug replicated: theta = head_index * freq (NOT position).
// freqs[i] = 10000^(-i/31) for i<32; zero for i in [32,64) -> those dims unchanged.
__global__ __launch_bounds__(256)
void rope_kernel(ushort_t* __restrict__ Q, ushort_t* __restrict__ K) {
  const int idx = blockIdx.x * 256 + threadIdx.x;
  const int NQ = 4096 * 16 * 32;
  const int NK = 4096 * 4 * 32;
  ushort_t* p; int h, i;
  if (idx < NQ) {
    const int t = idx >> 9, r = idx & 511;   // 16 heads * 32 freqs
    h = r >> 5; i = r & 31;
    p = Q + (size_t)t * 2048 + h * 128;
  } else {
    const int j2 = idx - NQ;
    if (j2 >= NK) return;
    const int t = j2 >> 7, r = j2 & 127;     // 4 heads * 32 freqs
    h = r >> 5; i = r & 31;
    p = K + (size_t)t * 512 + h * 128;
  }
  const float f  = powf(10000.0f, -(float)i / 31.0f);
  const float th = (float)h * f;
  float sn, cs;
  sincosf(th, &sn, &cs);
  const float x1 = bf2f(p[i]), x2 = bf2f(p[i + 64]);
  p[i]      = f2bf(x1 * cs + x2 * sn);
  p[i + 64] = f2bf(-x1 * sn + x2 * cs);
}

// ---------------------------------------------------------------- flash attention
// Grid: x = q-tile (reversed for big-work-first), y = head, z = batch.
// Block = 4 waves; wave w owns 16 q-rows of a 64-row Q tile. KV tiles of 64.
// K LDS [64][128] (row 256B, 16 grp, XOR low3); V^T LDS [128][64] (row 128B, 8 grp).
// P round-trips through per-wave 16x64 LDS region (same-wave DS is in-order;
// explicit lgkmcnt(0) + memory clobber for safety).
__global__ __launch_bounds__(256, 2)
void attn_kernel(const ushort_t* __restrict__ Q, const ushort_t* __restrict__ K,
                 const ushort_t* __restrict__ Vt, ushort_t* __restrict__ AO) {
  __shared__ bf16x8 smem[2560];              // 40 KB
  char* Ks = (char*)smem;                    // 16 KB
  char* Vs = (char*)smem + 16384;            // 16 KB
  char* Ps = (char*)smem + 32768;            //  8 KB (2 KB per wave)
  const int tid  = threadIdx.x;
  const int lane = tid & 63;
  const int wave = tid >> 6;
  const int qt = (int)gridDim.x - 1 - (int)blockIdx.x;
  const int h  = blockIdx.y;
  const int b  = blockIdx.z;
  const int kh = h >> 2;                     // N_REP = 4
  const int q0 = qt * 64;
  const ushort_t* Qp = Q  + (size_t)b * 2048 * 2048 + (size_t)h  * 128;
  const ushort_t* Kp = K  + (size_t)b * 2048 * 512  + (size_t)kh * 128;
  const ushort_t* Vp = Vt + (size_t)b * 512 * 2048  + (size_t)kh * 128 * 2048;

  // Q fragments held in registers for the whole block row
  bf16x8 qf[4];
  {
    const int row = q0 + wave * 16 + (lane & 15);
    const ushort_t* qr = Qp + (size_t)row * 2048 + (lane >> 4) * 8;
    #pragma unroll
    for (int kki = 0; kki < 4; ++kki) qf[kki] = *(const bf16x8*)(qr + kki * 32);
  }

  float m_[4], l_[4];
  f32x4 oacc[8] = {};
  #pragma unroll
  for (int j = 0; j < 4; ++j) { m_[j] = -3.0e38f; l_[j] = 0.f; }

  const float scale = 0.08838834764831845f;  // 1/sqrt(128)
  const int ntiles = qt + 1;
  for (int ti = 0; ti < ntiles; ++ti) {
    const int kv0 = ti * 64;
    #pragma unroll
    for (int it = 0; it < 4; ++it) {
      const int chunk = it * 4 + wave;
      { // K tile
        const int r = chunk * 4 + (lane >> 4);
        const int g = (lane & 15) ^ (r & 7);
        gload_lds16(Kp + (size_t)(kv0 + r) * 512 + g * 8, Ks + chunk * 1024);
      }
      { // V^T tile
        const int r = chunk * 8 + (lane >> 3);
        const int g = (lane & 7) ^ (r & 7);
        gload_lds16(Vp + (size_t)r * 2048 + kv0 + g * 8, Vs + chunk * 1024);
      }
    }
    __syncthreads();

    // S = Q K^T  (16 rows x 64 keys per wave)
    f32x4 sacc[4] = {};
    #pragma unroll
    for (int n = 0; n < 4; ++n) {
      const int key = n * 16 + (lane & 15);
      #pragma unroll
      for (int kki = 0; kki < 4; ++kki) {
        const int g = ((kki << 2) + (lane >> 4)) ^ (key & 7);
        const bf16x8 kf = *(const bf16x8*)(Ks + key * 256 + g * 16);
        sacc[n] = MFMA_BF16(qf[kki], kf, sacc[n]);
      }
    }

    // scale + causal mask (only the diagonal tile needs masking)
    float s[4][4];
    const bool diag = (ti == ntiles - 1);
    #pragma unroll
    for (int n = 0; n < 4; ++n)
      #pragma unroll
      for (int j = 0; j < 4; ++j) {
        float v = sacc[n][j] * scale;
        if (diag) {
          const int col = kv0 + n * 16 + (lane & 15);
          const int row = q0 + wave * 16 + ((lane >> 4) << 2) + j;
          if (col > row) v = -3.0e38f;
        }
        s[n][j] = v;
      }

    // online softmax: rows live in 16-lane groups, 4 rows per group (reg j)
    float pmax[4];
    #pragma unroll
    for (int j = 0; j < 4; ++j)
      pmax[j] = fmaxf(fmaxf(s[0][j], s[1][j]), fmaxf(s[2][j], s[3][j]));
    #pragma unroll
    for (int mk = 1; mk < 16; mk <<= 1)
      #pragma unroll
      for (int j = 0; j < 4; ++j)
        pmax[j] = fmaxf(pmax[j], __shfl_xor(pmax[j], mk));

    float alpha[4], rs[4], p[4][4];
    #pragma unroll
    for (int j = 0; j < 4; ++j) {
      const float mn = fmaxf(m_[j], pmax[j]);
      alpha[j] = __expf(m_[j] - mn);
      m_[j] = mn;
      rs[j] = 0.f;
    }
    #pragma unroll
    for (int n = 0; n < 4; ++n)
      #pragma unroll
      for (int j = 0; j < 4; ++j) {
        p[n][j] = __expf(s[n][j] - m_[j]);
        rs[j] += p[n][j];
      }
    #pragma unroll
    for (int mk = 1; mk < 16; mk <<= 1)
      #pragma unroll
      for (int j = 0; j < 4; ++j)
        rs[j] += __shfl_xor(rs[j], mk);
    #pragma unroll
    for (int j = 0; j < 4; ++j)
      l_[j] = l_[j] * alpha[j] + rs[j];
    #pragma unroll
    for (int n = 0; n < 8; ++n)
      #pragma unroll
      for (int j = 0; j < 4; ++j)
        oacc[n][j] *= alpha[j];

    // P -> per-wave LDS (bf16, swizzled), read back as MFMA-A fragments
    char* Pw = Ps + wave * 2048;
    #pragma unroll
    for (int n = 0; n < 4; ++n)
      #pragma unroll
      for (int j = 0; j < 4; ++j) {
        const int prow = ((lane >> 4) << 2) + j;
        const int pg = ((n << 1) | ((lane >> 3) & 1)) ^ (prow & 7);
        *(ushort_t*)(Pw + prow * 128 + pg * 16 + (lane & 7) * 2) = f2bf(p[n][j]);
      }
    asm volatile("s_waitcnt lgkmcnt(0)" ::: "memory");
    bf16x8 pf[2];
    #pragma unroll
    for (int kki = 0; kki < 2; ++kki) {
      const int prow = lane & 15;
      const int pg = ((kki << 2) + (lane >> 4)) ^ (prow & 7);
      pf[kki] = *(const bf16x8*)(Pw + prow * 128 + pg * 16);
    }

    // O += P V
    #pragma unroll
    for (int n = 0; n < 8; ++n) {
      const int d = n * 16 + (lane & 15);
      #pragma unroll
      for (int kki = 0; kki < 2; ++kki) {
        const int g = ((kki << 2) + (lane >> 4)) ^ (d & 7);
        const bf16x8 vf = *(const bf16x8*)(Vs + d * 128 + g * 16);
        oacc[n] = MFMA_BF16(pf[kki], vf, oacc[n]);
      }
    }
    __syncthreads();
  }

  // epilogue: O / l, store bf16 to attention-output buffer (token-major)
  ushort_t* AOp = AO + (size_t)b * 2048 * 2048 + (size_t)h * 128;
  #pragma unroll
  for (int n = 0; n < 8; ++n)
    #pragma unroll
    for (int j = 0; j < 4; ++j) {
      const int row = q0 + wave * 16 + ((lane >> 4) << 2) + j;
      const int col = n * 16 + (lane & 15);
      AOp[(size_t)row * 2048 + col] = f2bf(oacc[n][j] / l_[j]);
    }
}

// ---------------------------------------------------------------- launch
extern "C" void kernel_launch(void* const* d_in, const int* in_sizes, int n_in,
                              void* d_out, int out_size, void* d_ws, size_t ws_size,
                              hipStream_t stream) {
  const float* x  = (const float*)d_in[0];
  const float* wq = (const float*)d_in[1];
  const float* wk = (const float*)d_in[2];
  const float* wv = (const float*)d_in[3];
  const float* wo = (const float*)d_in[4];
  float* out = (float*)d_out;
  char* ws = (char*)d_ws;

  // workspace layout (bytes), total 79,691,776
  ushort_t* xb  = (ushort_t*)(ws);               // x   bf16  4096x2048
  ushort_t* wqb = (ushort_t*)(ws + 16777216);    // wq  bf16  2048x2048
  ushort_t* wkb = (ushort_t*)(ws + 25165824);    // wk  bf16   512x2048
  ushort_t* wvb = (ushort_t*)(ws + 27262976);    // wv  bf16   512x2048
  ushort_t* wob = (ushort_t*)(ws + 29360128);    // wo  bf16  2048x2048
  ushort_t* Qb  = (ushort_t*)(ws + 37748736);    // Q   bf16  4096x2048 (post-RoPE)
  ushort_t* Kb  = (ushort_t*)(ws + 54525952);    // K   bf16  4096x512  (post-RoPE)
  ushort_t* Vtb = (ushort_t*)(ws + 58720256);    // V^T bf16  [2][512][2048]
  ushort_t* AOb = (ushort_t*)(ws + 62914560);    // attn out bf16 4096x2048

  cvt_kernel<<<dim3(8192, 5), 256, 0, stream>>>(x, wq, wk, wv, wo,
                                                xb, wqb, wkb, wvb, wob);
  gemm_bt<0><<<dim3(32, 16), 256, 0, stream>>>(xb, wqb, Qb,  4096, 2048, 2048);
  gemm_bt<0><<<dim3(32, 4),  256, 0, stream>>>(xb, wkb, Kb,  4096, 512,  2048);
  gemm_bt<2><<<dim3(32, 4),  256, 0, stream>>>(xb, wvb, Vtb, 4096, 512,  2048);
  rope_kernel<<<dim3(10240), 256, 0, stream>>>(Qb, Kb);
  attn_kernel<<<dim3(32, 16, 2), 256, 0, stream>>>(Qb, Kb, Vtb, AOb);
  gemm_bt<1><<<dim3(32, 16), 256, 0, stream>>>(AOb, wob, out, 4096, 2048, 2048);
}

// Round 2
// 274.704 us; speedup vs baseline: 1.2409x; 1.2409x over previous
//
#include <hip/hip_runtime.h>
#include <cstdint>
#include <cstddef>

typedef __attribute__((ext_vector_type(8))) short bf16x8;
typedef __attribute__((ext_vector_type(4))) float f32x4;
typedef __attribute__((ext_vector_type(16))) float f32x16;
typedef unsigned short ushort_t;

#define MFMA_BF16(a, b, c) __builtin_amdgcn_mfma_f32_16x16x32_bf16((a), (b), (c), 0, 0, 0)
#define MFMA32_BF16(a, b, c) __builtin_amdgcn_mfma_f32_32x32x16_bf16((a), (b), (c), 0, 0, 0)

__device__ __forceinline__ unsigned short f2bf(float f) {
  unsigned int u = __float_as_uint(f);
  u += 0x7fffu + ((u >> 16) & 1u);           // round-to-nearest-even
  return (unsigned short)(u >> 16);
}
__device__ __forceinline__ float bf2f(unsigned short h) {
  return __uint_as_float(((unsigned int)h) << 16);
}
__device__ __forceinline__ uint32_t packbf(float lo, float hi) {
  return (uint32_t)f2bf(lo) | ((uint32_t)f2bf(hi) << 16);
}

__device__ __forceinline__ void gload_lds16(const void* g, void* lds) {
  __builtin_amdgcn_global_load_lds(
      (const __attribute__((address_space(1))) void*)g,
      (__attribute__((address_space(3))) void*)lds, 16, 0, 0);
}

// ---------------------------------------------------------------- convert
__global__ __launch_bounds__(256)
void cvt_kernel(const float* __restrict__ x, const float* __restrict__ wq,
                const float* __restrict__ wk, const float* __restrict__ wv,
                const float* __restrict__ wo,
                ushort_t* __restrict__ xb, ushort_t* __restrict__ wqb,
                ushort_t* __restrict__ wkb, ushort_t* __restrict__ wvb,
                ushort_t* __restrict__ wob) {
  const float* src; ushort_t* dst; int n;
  switch (blockIdx.y) {
    case 0:  src = x;  dst = xb;  n = 8388608; break;
    case 1:  src = wq; dst = wqb; n = 4194304; break;
    case 2:  src = wk; dst = wkb; n = 1048576; break;
    case 3:  src = wv; dst = wvb; n = 1048576; break;
    default: src = wo; dst = wob; n = 4194304; break;
  }
  const int i = (int)(blockIdx.x * 256u + threadIdx.x) * 4;
  if (i >= n) return;
  const float4 v = *(const float4*)(src + i);
  union { unsigned short us[4]; unsigned long long u64; } pk;
  pk.us[0] = f2bf(v.x); pk.us[1] = f2bf(v.y);
  pk.us[2] = f2bf(v.z); pk.us[3] = f2bf(v.w);
  *(unsigned long long*)(dst + i) = pk.u64;
}

// ---------------------------------------------------------------- GEMM  C = A * B^T
// (unchanged from round 0 — passed; m97-class structure)
template<int WMODE>
__global__ __launch_bounds__(256, 2)
void gemm_bt(const ushort_t* __restrict__ A, const ushort_t* __restrict__ B,
             void* __restrict__ Cout, int M, int N, int K) {
  __shared__ bf16x8 smem[2048];              // 32 KB
  char* As = (char*)smem;                    // 16 KB
  char* Bs = (char*)smem + 16384;            // 16 KB
  const int tid  = threadIdx.x;
  const int lane = tid & 63;
  const int wave = tid >> 6;
  const int wr = wave >> 1, wc = wave & 1;
  const ushort_t* Abase = A + (size_t)blockIdx.x * 128 * K;
  const ushort_t* Bbase = B + (size_t)blockIdx.y * 128 * K;

  f32x4 acc[4][4] = {};

  for (int k0 = 0; k0 < K; k0 += 64) {
    #pragma unroll
    for (int it = 0; it < 4; ++it) {
      const int chunk = it * 4 + wave;       // 16 chunks of 1 KB per operand
      const int r  = chunk * 8 + (lane >> 3);
      const int cg = (lane & 7) ^ (r & 7);   // inverse-swizzled source group
      gload_lds16(Abase + (size_t)r * K + k0 + cg * 8, As + chunk * 1024);
      gload_lds16(Bbase + (size_t)r * K + k0 + cg * 8, Bs + chunk * 1024);
    }
    __syncthreads();

    bf16x8 af[2][4], bf_[2][4];
    #pragma unroll
    for (int kki = 0; kki < 2; ++kki) {
      #pragma unroll
      for (int m = 0; m < 4; ++m) {
        const int row = wr * 64 + m * 16 + (lane & 15);
        const int cg  = ((kki << 2) + (lane >> 4)) ^ (row & 7);
        af[kki][m] = *(const bf16x8*)(As + row * 128 + cg * 16);
      }
      #pragma unroll
      for (int n = 0; n < 4; ++n) {
        const int row = wc * 64 + n * 16 + (lane & 15);
        const int cg  = ((kki << 2) + (lane >> 4)) ^ (row & 7);
        bf_[kki][n] = *(const bf16x8*)(Bs + row * 128 + cg * 16);
      }
    }
    #pragma unroll
    for (int kki = 0; kki < 2; ++kki)
      #pragma unroll
      for (int m = 0; m < 4; ++m)
        #pragma unroll
        for (int n = 0; n < 4; ++n)
          acc[m][n] = MFMA_BF16(af[kki][m], bf_[kki][n], acc[m][n]);
    __syncthreads();
  }

  const int row0 = blockIdx.x * 128 + wr * 64;
  const int col0 = blockIdx.y * 128 + wc * 64;
  #pragma unroll
  for (int m = 0; m < 4; ++m) {
    #pragma unroll
    for (int n = 0; n < 4; ++n) {
      #pragma unroll
      for (int j = 0; j < 4; ++j) {
        const int gm = row0 + m * 16 + ((lane >> 4) << 2) + j;
        const int gn = col0 + n * 16 + (lane & 15);
        const float v = acc[m][n][j];
        if (WMODE == 0) {
          ((ushort_t*)Cout)[(size_t)gm * N + gn] = f2bf(v);
        } else if (WMODE == 1) {
          ((float*)Cout)[(size_t)gm * N + gn] = v;
        } else {
          const int bb = gm >> 11, t = gm & 2047;
          ((ushort_t*)Cout)[(size_t)bb * N * 2048 + (size_t)gn * 2048 + t] = f2bf(v);
        }
      }
    }
  }
}

// ---------------------------------------------------------------- RoPE (head-indexed!)
__global__ __launch_bounds__(256)
void rope_kernel(ushort_t* __restrict__ Q, ushort_t* __restrict__ K) {
  const int idx = blockIdx.x * 256 + threadIdx.x;
  const int NQ = 4096 * 16 * 32;
  const int NK = 4096 * 4 * 32;
  ushort_t* p; int h, i;
  if (idx < NQ) {
    const int t = idx >> 9, r = idx & 511;
    h = r >> 5; i = r & 31;
    p = Q + (size_t)t * 2048 + h * 128;
  } else {
    const int j2 = idx - NQ;
    if (j2 >= NK) return;
    const int t = j2 >> 7, r = j2 & 127;
    h = r >> 5; i = r & 31;
    p = K + (size_t)t * 512 + h * 128;
  }
  const float f  = powf(10000.0f, -(float)i / 31.0f);
  const float th = (float)h * f;
  float sn, cs;
  sincosf(th, &sn, &cs);
  const float x1 = bf2f(p[i]), x2 = bf2f(p[i + 64]);
  p[i]      = f2bf(x1 * cs + x2 * sn);
  p[i + 64] = f2bf(-x1 * sn + x2 * cs);
}

// ---------------------------------------------------------------- flash attention
// m214-style: 4 waves x QBLK=32 rows (128-row block), KVBLK=64, 32x32x16 MFMA.
// Swapped QK^T (mfma(K,Q)) -> lane holds P-row for q=lane&31 (32 of 64 keys;
// partner half-wave has the rest). Softmax: local tree + ONE shfl_xor(32).
// P -> PV A-frags via scalar bf16 pack + v_permlane32_swap_b32 (T12), no P LDS.
// Defer-max rescale (T13, THR=8). K/V LDS double-buffered, XOR-swizzled (rule 21).
__global__ __launch_bounds__(256, 2)
void attn_kernel(const ushort_t* __restrict__ Q, const ushort_t* __restrict__ K,
                 const ushort_t* __restrict__ Vt, ushort_t* __restrict__ AO) {
  __shared__ bf16x8 smem_v[4096];            // 64 KB: 2 x (16KB K + 16KB V^T)
  char* smem = (char*)smem_v;
  const int tid  = threadIdx.x;
  const int lane = tid & 63;
  const int wq   = tid >> 6;                 // wave id 0..3
  const int ql   = lane & 31;                // q within wave's 32-row tile
  const int hi   = lane >> 5;                // half-wave
  const int qt = (int)gridDim.x - 1 - (int)blockIdx.x;   // big-work-first
  const int h  = blockIdx.y;
  const int b  = blockIdx.z;
  const int kh = h >> 2;                     // N_REP = 4
  const int q0b = qt * 128;
  const int qmin_w = q0b + wq * 32;          // wave's first q row
  const int qmax_w = qmin_w + 31;            // wave's last q row
  const int qrow = qmin_w + ql;              // this lane's q row

  const ushort_t* Qp = Q  + (size_t)b * 2048 * 2048 + (size_t)h  * 128;
  const ushort_t* Kp = K  + (size_t)b * 2048 * 512  + (size_t)kh * 128;
  const ushort_t* Vp = Vt + (size_t)b * 512 * 2048  + (size_t)kh * 128 * 2048;

  // Q fragments: B-operand of swapped QK^T. lane: q=ql, dk = kstep*16 + hi*8 + e
  bf16x8 qf[8];
  #pragma unroll
  for (int ks = 0; ks < 8; ++ks)
    qf[ks] = *(const bf16x8*)(Qp + (size_t)qrow * 2048 + ks * 16 + hi * 8);

  float m_ = -3.0e38f, l_ = 0.f;
  f32x16 oacc[4] = {};                        // O[q=crow(r,hi)][d=dg*32+ql]

  const float scale = 0.08838834764831845f;   // 1/sqrt(128)
  const int ntiles = (qt + 1) * 2;

  // ---- stage tile 0 into buffer 0
  {
    char* Ks = smem;
    char* Vs = smem + 16384;
    #pragma unroll
    for (int it = 0; it < 4; ++it) {
      const int ck = it * 4 + wq;
      const int rK = ck * 4 + (lane >> 4);
      const int gK = (lane & 15) ^ (rK & 7);
      gload_lds16(Kp + (size_t)rK * 512 + gK * 8, Ks + ck * 1024);
      const int rV = ck * 8 + (lane >> 3);
      const int gV = (lane & 7) ^ (rV & 7);
      gload_lds16(Vp + (size_t)rV * 2048 + gV * 8, Vs + ck * 1024);
    }
  }
  asm volatile("s_waitcnt vmcnt(0)" ::: "memory");
  __syncthreads();

  int buf = 0;
  for (int ti = 0; ti < ntiles; ++ti) {
    const int kv0 = ti * 64;
    // ---- prefetch next tile into the other buffer (overlaps compute)
    if (ti + 1 < ntiles) {
      const int nkv0 = kv0 + 64;
      char* Ks = smem + (buf ^ 1) * 32768;
      char* Vs = Ks + 16384;
      #pragma unroll
      for (int it = 0; it < 4; ++it) {
        const int ck = it * 4 + wq;
        const int rK = ck * 4 + (lane >> 4);
        const int gK = (lane & 15) ^ (rK & 7);
        gload_lds16(Kp + (size_t)(nkv0 + rK) * 512 + gK * 8, Ks + ck * 1024);
        const int rV = ck * 8 + (lane >> 3);
        const int gV = (lane & 7) ^ (rV & 7);
        gload_lds16(Vp + (size_t)rV * 2048 + nkv0 + gV * 8, Vs + ck * 1024);
      }
    }

    char* Ks = smem + buf * 32768;
    char* Vs = Ks + 16384;
    if (kv0 <= qmax_w) {                      // wave-uniform activity gate
      // ---- QK^T (swapped): sacc[kg] = S^T[key=kg*32+crow][q=ql]
      f32x16 sacc[2] = {};
      #pragma unroll
      for (int kg = 0; kg < 2; ++kg) {
        const int key = kg * 32 + ql;
        #pragma unroll
        for (int ks = 0; ks < 8; ++ks) {
          const int g = ((ks << 1) + hi) ^ (key & 7);
          const bf16x8 kf = *(const bf16x8*)(Ks + key * 256 + g * 16);
          sacc[kg] = MFMA32_BF16(kf, qf[ks], sacc[kg]);
        }
      }

      // ---- scale + causal mask
      const bool domask = (kv0 + 63 > qmin_w);
      #pragma unroll
      for (int kg = 0; kg < 2; ++kg)
        #pragma unroll
        for (int r = 0; r < 16; ++r) {
          float v = sacc[kg][r] * scale;
          if (domask) {
            const int keyg = kv0 + kg * 32 + (r & 3) + 8 * (r >> 2) + 4 * hi;
            if (keyg > qrow) v = -3.0e38f;
          }
          sacc[kg][r] = v;
        }

      // ---- online softmax (row is lane-local; partner half has other 32 keys)
      float pm = sacc[0][0];
      #pragma unroll
      for (int kg = 0; kg < 2; ++kg)
        #pragma unroll
        for (int r = 0; r < 16; ++r) pm = fmaxf(pm, sacc[kg][r]);
      pm = fmaxf(pm, __shfl_xor(pm, 32));

      if (__any(pm > m_ + 8.0f)) {            // T13 defer-max
        const float mn = fmaxf(m_, pm);
        const float alpha = __expf(m_ - mn);
        m_ = mn;
        l_ *= alpha;
        #pragma unroll
        for (int r = 0; r < 16; ++r) {
          const float ar = __shfl(alpha, (r & 3) + 8 * (r >> 2) + 4 * hi);
          #pragma unroll
          for (int dg = 0; dg < 4; ++dg) oacc[dg][r] *= ar;
        }
      }

      float rs = 0.f;
      #pragma unroll
      for (int kg = 0; kg < 2; ++kg)
        #pragma unroll
        for (int r = 0; r < 16; ++r) {
          const float p = __expf(sacc[kg][r] - m_);
          sacc[kg][r] = p;
          rs += p;
        }
      rs += __shfl_xor(rs, 32);
      l_ += rs;

      // ---- P -> A-fragments via pack + permlane32_swap (T12)
      bf16x8 pa[4];
      #pragma unroll
      for (int ks = 0; ks < 4; ++ks) {
        const int kg = ks >> 1;
        const int base = 8 * (ks & 1);
        union { uint32_t w[4]; bf16x8 v; } U;
        #pragma unroll
        for (int j = 0; j < 2; ++j) {
          uint32_t a  = packbf(sacc[kg][base + 2 * j],     sacc[kg][base + 2 * j + 1]);
          uint32_t bb = packbf(sacc[kg][base + 4 + 2 * j], sacc[kg][base + 4 + 2 * j + 1]);
          asm volatile("v_permlane32_swap_b32 %0, %1" : "+v"(a), "+v"(bb));
          U.w[j] = a; U.w[2 + j] = bb;
        }
        pa[ks] = U.v;
      }

      // ---- O += P V   (A=pa, B=V-frag from V^T LDS)
      #pragma unroll
      for (int dg = 0; dg < 4; ++dg) {
        const int d = dg * 32 + ql;
        #pragma unroll
        for (int ks = 0; ks < 4; ++ks) {
          const int g = ((ks << 1) + hi) ^ (d & 7);
          const bf16x8 vf = *(const bf16x8*)(Vs + d * 128 + g * 16);
          oacc[dg] = MFMA32_BF16(pa[ks], vf, oacc[dg]);
        }
      }
    }

    asm volatile("s_waitcnt vmcnt(0)" ::: "memory");  // next-tile loads landed
    __syncthreads();                                  // all waves done with buf
    buf ^= 1;
  }

  // ---- epilogue: normalize, store bf16 (coalesced 64B per half-wave)
  const float linv = 1.0f / l_;
  ushort_t* AOp = AO + (size_t)b * 2048 * 2048 + (size_t)h * 128;
  #pragma unroll
  for (int r = 0; r < 16; ++r) {
    const int cr = (r & 3) + 8 * (r >> 2) + 4 * hi;
    const float li = __shfl(linv, cr);
    const int row = q0b + wq * 32 + cr;
    #pragma unroll
    for (int dg = 0; dg < 4; ++dg)
      AOp[(size_t)row * 2048 + dg * 32 + ql] = f2bf(oacc[dg][r] * li);
  }
}

// ---------------------------------------------------------------- launch
extern "C" void kernel_launch(void* const* d_in, const int* in_sizes, int n_in,
                              void* d_out, int out_size, void* d_ws, size_t ws_size,
                              hipStream_t stream) {
  const float* x  = (const float*)d_in[0];
  const float* wq = (const float*)d_in[1];
  const float* wk = (const float*)d_in[2];
  const float* wv = (const float*)d_in[3];
  const float* wo = (const float*)d_in[4];
  float* out = (float*)d_out;
  char* ws = (char*)d_ws;

  ushort_t* xb  = (ushort_t*)(ws);               // x   bf16  4096x2048
  ushort_t* wqb = (ushort_t*)(ws + 16777216);    // wq  bf16  2048x2048
  ushort_t* wkb = (ushort_t*)(ws + 25165824);    // wk  bf16   512x2048
  ushort_t* wvb = (ushort_t*)(ws + 27262976);    // wv  bf16   512x2048
  ushort_t* wob = (ushort_t*)(ws + 29360128);    // wo  bf16  2048x2048
  ushort_t* Qb  = (ushort_t*)(ws + 37748736);    // Q   bf16  4096x2048 (post-RoPE)
  ushort_t* Kb  = (ushort_t*)(ws + 54525952);    // K   bf16  4096x512  (post-RoPE)
  ushort_t* Vtb = (ushort_t*)(ws + 58720256);    // V^T bf16  [2][512][2048]
  ushort_t* AOb = (ushort_t*)(ws + 62914560);    // attn out bf16 4096x2048

  cvt_kernel<<<dim3(8192, 5), 256, 0, stream>>>(x, wq, wk, wv, wo,
                                                xb, wqb, wkb, wvb, wob);
  gemm_bt<0><<<dim3(32, 16), 256, 0, stream>>>(xb, wqb, Qb,  4096, 2048, 2048);
  gemm_bt<0><<<dim3(32, 4),  256, 0, stream>>>(xb, wkb, Kb,  4096, 512,  2048);
  gemm_bt<2><<<dim3(32, 4),  256, 0, stream>>>(xb, wvb, Vtb, 4096, 512,  2048);
  rope_kernel<<<dim3(10240), 256, 0, stream>>>(Qb, Kb);
  attn_kernel<<<dim3(16, 16, 2), 256, 0, stream>>>(Qb, Kb, Vtb, AOb);
  gemm_bt<1><<<dim3(32, 16), 256, 0, stream>>>(AOb, wob, out, 4096, 2048, 2048);
}

// Round 4
// 249.114 us; speedup vs baseline: 1.3684x; 1.1027x over previous
//
#include <hip/hip_runtime.h>
#include <cstdint>
#include <cstddef>

typedef __attribute__((ext_vector_type(8))) short bf16x8;
typedef __attribute__((ext_vector_type(4))) float f32x4;
typedef __attribute__((ext_vector_type(16))) float f32x16;
typedef unsigned short ushort_t;

#define MFMA_BF16(a, b, c) __builtin_amdgcn_mfma_f32_16x16x32_bf16((a), (b), (c), 0, 0, 0)
#define MFMA32_BF16(a, b, c) __builtin_amdgcn_mfma_f32_32x32x16_bf16((a), (b), (c), 0, 0, 0)

__device__ __forceinline__ unsigned short f2bf(float f) {
  unsigned int u = __float_as_uint(f);
  u += 0x7fffu + ((u >> 16) & 1u);           // round-to-nearest-even
  return (unsigned short)(u >> 16);
}
__device__ __forceinline__ float bf2f(unsigned short h) {
  return __uint_as_float(((unsigned int)h) << 16);
}
__device__ __forceinline__ uint32_t packbf(float lo, float hi) {
  return (uint32_t)f2bf(lo) | ((uint32_t)f2bf(hi) << 16);
}

__device__ __forceinline__ void gload_lds16(const void* g, void* lds) {
  __builtin_amdgcn_global_load_lds(
      (const __attribute__((address_space(1))) void*)g,
      (__attribute__((address_space(3))) void*)lds, 16, 0, 0);
}

// ---------------------------------------------------------------- convert
__global__ __launch_bounds__(256)
void cvt_kernel(const float* __restrict__ x, const float* __restrict__ wq,
                const float* __restrict__ wk, const float* __restrict__ wv,
                const float* __restrict__ wo,
                ushort_t* __restrict__ xb, ushort_t* __restrict__ wqb,
                ushort_t* __restrict__ wkb, ushort_t* __restrict__ wvb,
                ushort_t* __restrict__ wob) {
  const float* src; ushort_t* dst; int n;
  switch (blockIdx.y) {
    case 0:  src = x;  dst = xb;  n = 8388608; break;
    case 1:  src = wq; dst = wqb; n = 4194304; break;
    case 2:  src = wk; dst = wkb; n = 1048576; break;
    case 3:  src = wv; dst = wvb; n = 1048576; break;
    default: src = wo; dst = wob; n = 4194304; break;
  }
  const int i = (int)(blockIdx.x * 256u + threadIdx.x) * 4;
  if (i >= n) return;
  const float4 v = *(const float4*)(src + i);
  union { unsigned short us[4]; unsigned long long u64; } pk;
  pk.us[0] = f2bf(v.x); pk.us[1] = f2bf(v.y);
  pk.us[2] = f2bf(v.z); pk.us[3] = f2bf(v.w);
  *(unsigned long long*)(dst + i) = pk.u64;
}

// ---------------------------------------------------------------- GEMM  C = A * B^T
// T3 minimal 2-phase (drain0, race-free by construction): double-buffered LDS,
// prefetch(t+1) issued BEFORE compute(t), ONE __syncthreads per K-step. The
// __syncthreads vmcnt(0)+lgkmcnt(0) drain means no memory op crosses a barrier.
template<int WMODE>
__global__ __launch_bounds__(256, 2)
void gemm_bt(const ushort_t* __restrict__ A, const ushort_t* __restrict__ B,
             void* __restrict__ Cout, int M, int N, int K) {
  __shared__ bf16x8 smem_v[4096];            // 64 KB: 2 x (16KB A + 16KB B)
  char* smem = (char*)smem_v;
  const int tid  = threadIdx.x;
  const int lane = tid & 63;
  const int wave = tid >> 6;
  const int wr = wave >> 1, wc = wave & 1;
  const ushort_t* Abase = A + (size_t)blockIdx.x * 128 * K;
  const ushort_t* Bbase = B + (size_t)blockIdx.y * 128 * K;

  f32x4 acc[4][4] = {};
  const int nk = K >> 6;

  // prologue: stage K-step 0 into buffer 0, full drain + sync
  #pragma unroll
  for (int it = 0; it < 4; ++it) {
    const int chunk = it * 4 + wave;
    const int r  = chunk * 8 + (lane >> 3);
    const int cg = (lane & 7) ^ (r & 7);
    gload_lds16(Abase + (size_t)r * K + cg * 8, smem + chunk * 1024);
    gload_lds16(Bbase + (size_t)r * K + cg * 8, smem + 16384 + chunk * 1024);
  }
  __syncthreads();

  for (int t = 0; t < nk; ++t) {
    // issue next-tile stage FIRST (overlaps with this tile's compute);
    // writes the buffer whose reads completed before the PREVIOUS barrier.
    if (t + 1 < nk) {
      char* dst = smem + ((t + 1) & 1) * 32768;
      const int k0 = (t + 1) * 64;
      #pragma unroll
      for (int it = 0; it < 4; ++it) {
        const int chunk = it * 4 + wave;
        const int r  = chunk * 8 + (lane >> 3);
        const int cg = (lane & 7) ^ (r & 7);
        gload_lds16(Abase + (size_t)r * K + k0 + cg * 8, dst + chunk * 1024);
        gload_lds16(Bbase + (size_t)r * K + k0 + cg * 8, dst + 16384 + chunk * 1024);
      }
    }

    char* As = smem + (t & 1) * 32768;
    char* Bs = As + 16384;
    bf16x8 af[2][4], bf_[2][4];
    #pragma unroll
    for (int kki = 0; kki < 2; ++kki) {
      #pragma unroll
      for (int m = 0; m < 4; ++m) {
        const int row = wr * 64 + m * 16 + (lane & 15);
        const int cg  = ((kki << 2) + (lane >> 4)) ^ (row & 7);
        af[kki][m] = *(const bf16x8*)(As + row * 128 + cg * 16);
      }
      #pragma unroll
      for (int n = 0; n < 4; ++n) {
        const int row = wc * 64 + n * 16 + (lane & 15);
        const int cg  = ((kki << 2) + (lane >> 4)) ^ (row & 7);
        bf_[kki][n] = *(const bf16x8*)(Bs + row * 128 + cg * 16);
      }
    }
    #pragma unroll
    for (int kki = 0; kki < 2; ++kki)
      #pragma unroll
      for (int m = 0; m < 4; ++m)
        #pragma unroll
        for (int n = 0; n < 4; ++n)
          acc[m][n] = MFMA_BF16(af[kki][m], bf_[kki][n], acc[m][n]);

    __syncthreads();   // drains vmcnt(0): stage(t+1) landed; all waves done with buf t
  }

  const int row0 = blockIdx.x * 128 + wr * 64;
  const int col0 = blockIdx.y * 128 + wc * 64;
  #pragma unroll
  for (int m = 0; m < 4; ++m) {
    #pragma unroll
    for (int n = 0; n < 4; ++n) {
      #pragma unroll
      for (int j = 0; j < 4; ++j) {
        const int gm = row0 + m * 16 + ((lane >> 4) << 2) + j;
        const int gn = col0 + n * 16 + (lane & 15);
        const float v = acc[m][n][j];
        if (WMODE == 0) {
          ((ushort_t*)Cout)[(size_t)gm * N + gn] = f2bf(v);
        } else if (WMODE == 1) {
          ((float*)Cout)[(size_t)gm * N + gn] = v;
        } else {
          const int bb = gm >> 11, t2 = gm & 2047;
          ((ushort_t*)Cout)[(size_t)bb * N * 2048 + (size_t)gn * 2048 + t2] = f2bf(v);
        }
      }
    }
  }
}

// ---------------------------------------------------------------- RoPE for K only
// (Q RoPE is fused into attn_kernel's Q-load.) Head-indexed theta per reference.
__global__ __launch_bounds__(256)
void rope_k_kernel(ushort_t* __restrict__ K) {
  const int idx = blockIdx.x * 256 + threadIdx.x;
  const int NK = 4096 * 4 * 32;
  if (idx >= NK) return;
  const int t = idx >> 7, r = idx & 127;
  const int h = r >> 5, i = r & 31;
  ushort_t* p = K + (size_t)t * 512 + h * 128;
  const float f  = powf(10000.0f, -(float)i / 31.0f);
  const float th = (float)h * f;
  float sn, cs;
  sincosf(th, &sn, &cs);
  const float x1 = bf2f(p[i]), x2 = bf2f(p[i + 64]);
  p[i]      = f2bf(x1 * cs + x2 * sn);
  p[i + 64] = f2bf(-x1 * sn + x2 * cs);
}

// ---------------------------------------------------------------- flash attention
// 4 waves x 32 q-rows, KVBLK=64, 32x32x16 MFMA, swapped QK^T, in-register
// softmax + permlane P-distribution (T12), defer-max (T13), fused Q-RoPE.
// Sync: T3 minimal 2-phase — prefetch issued first, ONE __syncthreads per tile
// (full drain; no memory op crosses a barrier). setprio(T5) around MFMA runs.
__global__ __launch_bounds__(256, 2)
void attn_kernel(const ushort_t* __restrict__ Q, const ushort_t* __restrict__ K,
                 const ushort_t* __restrict__ Vt, ushort_t* __restrict__ AO) {
  __shared__ bf16x8 smem_v[4096];            // 64 KB: 2 x (16KB K + 16KB V^T)
  char* smem = (char*)smem_v;
  const int tid  = threadIdx.x;
  const int lane = tid & 63;
  const int wq   = tid >> 6;
  const int ql   = lane & 31;
  const int hi   = lane >> 5;
  const int qt = (int)gridDim.x - 1 - (int)blockIdx.x;   // big-work-first
  const int h  = blockIdx.y;
  const int b  = blockIdx.z;
  const int kh = h >> 2;                     // N_REP = 4
  const int q0b = qt * 128;
  const int qmin_w = q0b + wq * 32;
  const int qmax_w = qmin_w + 31;
  const int qrow = qmin_w + ql;

  const ushort_t* Qp = Q  + (size_t)b * 2048 * 2048 + (size_t)h  * 128;
  const ushort_t* Kp = K  + (size_t)b * 2048 * 512  + (size_t)kh * 128;
  const ushort_t* Vp = Vt + (size_t)b * 512 * 2048  + (size_t)kh * 128 * 2048;

  const int ntiles = (qt + 1) * 2;

  // ---- stage tile 0 into buffer 0 (issued before Q loads so HBM latency
  //      hides under the Q-load + RoPE prologue)
  #pragma unroll
  for (int it = 0; it < 4; ++it) {
    const int ck = it * 4 + wq;
    const int rK = ck * 4 + (lane >> 4);
    const int gK = (lane & 15) ^ (rK & 7);
    gload_lds16(Kp + (size_t)rK * 512 + gK * 8, smem + ck * 1024);
    const int rV = ck * 8 + (lane >> 3);
    const int gV = (lane & 7) ^ (rV & 7);
    gload_lds16(Vp + (size_t)rV * 2048 + gV * 8, smem + 16384 + ck * 1024);
  }

  // ---- load Q fragments + fused head-indexed RoPE (pairs are lane-local)
  bf16x8 qf[8];
  #pragma unroll
  for (int ks = 0; ks < 8; ++ks)
    qf[ks] = *(const bf16x8*)(Qp + (size_t)qrow * 2048 + ks * 16 + hi * 8);
  #pragma unroll
  for (int ks = 0; ks < 2; ++ks) {
    union { bf16x8 v; ushort_t us[8]; } X1, X2;
    X1.v = qf[ks]; X2.v = qf[ks + 4];
    #pragma unroll
    for (int e = 0; e < 8; ++e) {
      const int i = ks * 16 + hi * 8 + e;
      const float f = __expf(-(float)i * (9.2103403720f / 31.0f));  // 10000^(-i/31)
      float sn, cs;
      sincosf((float)h * f, &sn, &cs);
      const float x1 = bf2f(X1.us[e]), x2 = bf2f(X2.us[e]);
      X1.us[e] = f2bf(x1 * cs + x2 * sn);
      X2.us[e] = f2bf(-x1 * sn + x2 * cs);
    }
    qf[ks] = X1.v; qf[ks + 4] = X2.v;
  }

  float m_ = -3.0e38f, l_ = 0.f;
  f32x16 oacc[4] = {};
  const float scale = 0.08838834764831845f;  // 1/sqrt(128)

  __syncthreads();                           // tile 0 landed (full drain)

  for (int ti = 0; ti < ntiles; ++ti) {
    const int kv0 = ti * 64;
    // ---- issue next-tile stage first (overlaps this tile's compute)
    if (ti + 1 < ntiles) {
      const int nkv0 = kv0 + 64;
      char* dst = smem + ((ti + 1) & 1) * 32768;
      #pragma unroll
      for (int it = 0; it < 4; ++it) {
        const int ck = it * 4 + wq;
        const int rK = ck * 4 + (lane >> 4);
        const int gK = (lane & 15) ^ (rK & 7);
        gload_lds16(Kp + (size_t)(nkv0 + rK) * 512 + gK * 8, dst + ck * 1024);
        const int rV = ck * 8 + (lane >> 3);
        const int gV = (lane & 7) ^ (rV & 7);
        gload_lds16(Vp + (size_t)rV * 2048 + nkv0 + gV * 8, dst + 16384 + ck * 1024);
      }
    }

    char* Ks = smem + (ti & 1) * 32768;
    char* Vs = Ks + 16384;
    if (kv0 <= qmax_w) {                     // wave-uniform activity gate
      // ---- QK^T (swapped): lane holds S^T[key][q=ql]
      f32x16 sacc[2] = {};
      __builtin_amdgcn_s_setprio(1);
      #pragma unroll
      for (int kg = 0; kg < 2; ++kg) {
        const int key = kg * 32 + ql;
        #pragma unroll
        for (int ks = 0; ks < 8; ++ks) {
          const int g = ((ks << 1) + hi) ^ (key & 7);
          const bf16x8 kf = *(const bf16x8*)(Ks + key * 256 + g * 16);
          sacc[kg] = MFMA32_BF16(kf, qf[ks], sacc[kg]);
        }
      }
      __builtin_amdgcn_s_setprio(0);

      // ---- scale + causal mask
      const bool domask = (kv0 + 63 > qmin_w);
      #pragma unroll
      for (int kg = 0; kg < 2; ++kg)
        #pragma unroll
        for (int r = 0; r < 16; ++r) {
          float v = sacc[kg][r] * scale;
          if (domask) {
            const int keyg = kv0 + kg * 32 + (r & 3) + 8 * (r >> 2) + 4 * hi;
            if (keyg > qrow) v = -3.0e38f;
          }
          sacc[kg][r] = v;
        }

      // ---- online softmax (row lane-local; partner half has other 32 keys)
      float pm = sacc[0][0];
      #pragma unroll
      for (int kg = 0; kg < 2; ++kg)
        #pragma unroll
        for (int r = 0; r < 16; ++r) pm = fmaxf(pm, sacc[kg][r]);
      pm = fmaxf(pm, __shfl_xor(pm, 32));

      if (__any(pm > m_ + 8.0f)) {           // T13 defer-max
        const float mn = fmaxf(m_, pm);
        const float alpha = __expf(m_ - mn);
        m_ = mn;
        l_ *= alpha;
        #pragma unroll
        for (int r = 0; r < 16; ++r) {
          const float ar = __shfl(alpha, (r & 3) + 8 * (r >> 2) + 4 * hi);
          #pragma unroll
          for (int dg = 0; dg < 4; ++dg) oacc[dg][r] *= ar;
        }
      }

      float rs = 0.f;
      #pragma unroll
      for (int kg = 0; kg < 2; ++kg)
        #pragma unroll
        for (int r = 0; r < 16; ++r) {
          const float p = __expf(sacc[kg][r] - m_);
          sacc[kg][r] = p;
          rs += p;
        }
      rs += __shfl_xor(rs, 32);
      l_ += rs;

      // ---- P -> A-fragments via pack + permlane32_swap (T12)
      bf16x8 pa[4];
      #pragma unroll
      for (int ks = 0; ks < 4; ++ks) {
        const int kg = ks >> 1;
        const int base = 8 * (ks & 1);
        union { uint32_t w[4]; bf16x8 v; } U;
        #pragma unroll
        for (int j = 0; j < 2; ++j) {
          uint32_t a  = packbf(sacc[kg][base + 2 * j],     sacc[kg][base + 2 * j + 1]);
          uint32_t bb = packbf(sacc[kg][base + 4 + 2 * j], sacc[kg][base + 4 + 2 * j + 1]);
          asm volatile("v_permlane32_swap_b32 %0, %1" : "+v"(a), "+v"(bb));
          U.w[j] = a; U.w[2 + j] = bb;
        }
        pa[ks] = U.v;
      }

      // ---- O += P V
      __builtin_amdgcn_s_setprio(1);
      #pragma unroll
      for (int dg = 0; dg < 4; ++dg) {
        const int d = dg * 32 + ql;
        #pragma unroll
        for (int ks = 0; ks < 4; ++ks) {
          const int g = ((ks << 1) + hi) ^ (d & 7);
          const bf16x8 vf = *(const bf16x8*)(Vs + d * 128 + g * 16);
          oacc[dg] = MFMA32_BF16(pa[ks], vf, oacc[dg]);
        }
      }
      __builtin_amdgcn_s_setprio(0);
    }

    __syncthreads();   // drains vmcnt(0): stage(ti+1) landed; all waves done with buf
  }

  // ---- epilogue: normalize, store bf16
  const float linv = 1.0f / l_;
  ushort_t* AOp = AO + (size_t)b * 2048 * 2048 + (size_t)h * 128;
  #pragma unroll
  for (int r = 0; r < 16; ++r) {
    const int cr = (r & 3) + 8 * (r >> 2) + 4 * hi;
    const float li = __shfl(linv, cr);
    const int row = q0b + wq * 32 + cr;
    #pragma unroll
    for (int dg = 0; dg < 4; ++dg)
      AOp[(size_t)row * 2048 + dg * 32 + ql] = f2bf(oacc[dg][r] * li);
  }
}

// ---------------------------------------------------------------- launch
extern "C" void kernel_launch(void* const* d_in, const int* in_sizes, int n_in,
                              void* d_out, int out_size, void* d_ws, size_t ws_size,
                              hipStream_t stream) {
  const float* x  = (const float*)d_in[0];
  const float* wq = (const float*)d_in[1];
  const float* wk = (const float*)d_in[2];
  const float* wv = (const float*)d_in[3];
  const float* wo = (const float*)d_in[4];
  float* out = (float*)d_out;
  char* ws = (char*)d_ws;

  ushort_t* xb  = (ushort_t*)(ws);               // x   bf16  4096x2048
  ushort_t* wqb = (ushort_t*)(ws + 16777216);    // wq  bf16  2048x2048
  ushort_t* wkb = (ushort_t*)(ws + 25165824);    // wk  bf16   512x2048
  ushort_t* wvb = (ushort_t*)(ws + 27262976);    // wv  bf16   512x2048
  ushort_t* wob = (ushort_t*)(ws + 29360128);    // wo  bf16  2048x2048
  ushort_t* Qb  = (ushort_t*)(ws + 37748736);    // Q   bf16  4096x2048 (pre-RoPE)
  ushort_t* Kb  = (ushort_t*)(ws + 54525952);    // K   bf16  4096x512  (post-RoPE)
  ushort_t* Vtb = (ushort_t*)(ws + 58720256);    // V^T bf16  [2][512][2048]
  ushort_t* AOb = (ushort_t*)(ws + 62914560);    // attn out bf16 4096x2048

  cvt_kernel<<<dim3(8192, 5), 256, 0, stream>>>(x, wq, wk, wv, wo,
                                                xb, wqb, wkb, wvb, wob);
  gemm_bt<0><<<dim3(32, 16), 256, 0, stream>>>(xb, wqb, Qb,  4096, 2048, 2048);
  gemm_bt<0><<<dim3(32, 4),  256, 0, stream>>>(xb, wkb, Kb,  4096, 512,  2048);
  gemm_bt<2><<<dim3(32, 4),  256, 0, stream>>>(xb, wvb, Vtb, 4096, 512,  2048);
  rope_k_kernel<<<dim3(2048), 256, 0, stream>>>(Kb);
  attn_kernel<<<dim3(16, 16, 2), 256, 0, stream>>>(Qb, Kb, Vtb, AOb);
  gemm_bt<1><<<dim3(32, 16), 256, 0, stream>>>(AOb, wob, out, 4096, 2048, 2048);
}

// Round 5
// 207.696 us; speedup vs baseline: 1.6413x; 1.1994x over previous
//
#include <hip/hip_runtime.h>
#include <cstdint>
#include <cstddef>

typedef __attribute__((ext_vector_type(8))) short bf16x8;
typedef __attribute__((ext_vector_type(4))) float f32x4;
typedef __attribute__((ext_vector_type(16))) float f32x16;
typedef unsigned short ushort_t;

#define MFMA_BF16(a, b, c) __builtin_amdgcn_mfma_f32_16x16x32_bf16((a), (b), (c), 0, 0, 0)
#define MFMA32_BF16(a, b, c) __builtin_amdgcn_mfma_f32_32x32x16_bf16((a), (b), (c), 0, 0, 0)

__device__ __forceinline__ unsigned short f2bf(float f) {
  unsigned int u = __float_as_uint(f);
  u += 0x7fffu + ((u >> 16) & 1u);           // round-to-nearest-even
  return (unsigned short)(u >> 16);
}
__device__ __forceinline__ float bf2f(unsigned short h) {
  return __uint_as_float(((unsigned int)h) << 16);
}
__device__ __forceinline__ uint32_t packbf(float lo, float hi) {
  return (uint32_t)f2bf(lo) | ((uint32_t)f2bf(hi) << 16);
}

__device__ __forceinline__ void gload_lds16(const void* g, void* lds) {
  __builtin_amdgcn_global_load_lds(
      (const __attribute__((address_space(1))) void*)g,
      (__attribute__((address_space(3))) void*)lds, 16, 0, 0);
}

// ---------------------------------------------------------------- convert
__global__ __launch_bounds__(256)
void cvt_kernel(const float* __restrict__ x, const float* __restrict__ wq,
                const float* __restrict__ wk, const float* __restrict__ wv,
                const float* __restrict__ wo,
                ushort_t* __restrict__ xb, ushort_t* __restrict__ wqb,
                ushort_t* __restrict__ wkb, ushort_t* __restrict__ wvb,
                ushort_t* __restrict__ wob) {
  const float* src; ushort_t* dst; int n;
  switch (blockIdx.y) {
    case 0:  src = x;  dst = xb;  n = 8388608; break;
    case 1:  src = wq; dst = wqb; n = 4194304; break;
    case 2:  src = wk; dst = wkb; n = 1048576; break;
    case 3:  src = wv; dst = wvb; n = 1048576; break;
    default: src = wo; dst = wob; n = 4194304; break;
  }
  const int i = (int)(blockIdx.x * 256u + threadIdx.x) * 4;
  if (i >= n) return;
  const float4 v = *(const float4*)(src + i);
  union { unsigned short us[4]; unsigned long long u64; } pk;
  pk.us[0] = f2bf(v.x); pk.us[1] = f2bf(v.y);
  pk.us[2] = f2bf(v.z); pk.us[3] = f2bf(v.w);
  *(unsigned long long*)(dst + i) = pk.u64;
}

// ---------------------------------------------------------------- fused QKV GEMM
// One launch for Q/K/V projections (768 blocks vs 512+128+128 serialized —
// K/V launches previously idled >half the machine for a full block-duration).
// Body identical to gemm_bt (T3 minimal 2-phase, race-free drain sync).
// blockIdx.y: 0..15 -> Q (N=2048), 16..19 -> K (N=512), 20..23 -> V^T (N=512).
__global__ __launch_bounds__(256, 2)
void gemm_qkv(const ushort_t* __restrict__ A,
              const ushort_t* __restrict__ WQ, const ushort_t* __restrict__ WK,
              const ushort_t* __restrict__ WV,
              ushort_t* __restrict__ Qb, ushort_t* __restrict__ Kb,
              ushort_t* __restrict__ Vtb) {
  __shared__ bf16x8 smem_v[4096];            // 64 KB
  char* smem = (char*)smem_v;
  const int tid  = threadIdx.x;
  const int lane = tid & 63;
  const int wave = tid >> 6;
  const int wr = wave >> 1, wc = wave & 1;
  const int y = blockIdx.y;
  int mode, ylocal;
  const ushort_t* Bsel;
  if (y < 16)      { mode = 0; ylocal = y;      Bsel = WQ; }
  else if (y < 20) { mode = 1; ylocal = y - 16; Bsel = WK; }
  else             { mode = 2; ylocal = y - 20; Bsel = WV; }
  const ushort_t* Abase = A + (size_t)blockIdx.x * 128 * 2048;
  const ushort_t* Bbase = Bsel + (size_t)ylocal * 128 * 2048;

  f32x4 acc[4][4] = {};

  #pragma unroll
  for (int it = 0; it < 4; ++it) {
    const int chunk = it * 4 + wave;
    const int r  = chunk * 8 + (lane >> 3);
    const int cg = (lane & 7) ^ (r & 7);
    gload_lds16(Abase + (size_t)r * 2048 + cg * 8, smem + chunk * 1024);
    gload_lds16(Bbase + (size_t)r * 2048 + cg * 8, smem + 16384 + chunk * 1024);
  }
  __syncthreads();

  for (int t = 0; t < 32; ++t) {
    if (t + 1 < 32) {
      char* dst = smem + ((t + 1) & 1) * 32768;
      const int k0 = (t + 1) * 64;
      #pragma unroll
      for (int it = 0; it < 4; ++it) {
        const int chunk = it * 4 + wave;
        const int r  = chunk * 8 + (lane >> 3);
        const int cg = (lane & 7) ^ (r & 7);
        gload_lds16(Abase + (size_t)r * 2048 + k0 + cg * 8, dst + chunk * 1024);
        gload_lds16(Bbase + (size_t)r * 2048 + k0 + cg * 8, dst + 16384 + chunk * 1024);
      }
    }

    char* As = smem + (t & 1) * 32768;
    char* Bs = As + 16384;
    bf16x8 af[2][4], bf_[2][4];
    #pragma unroll
    for (int kki = 0; kki < 2; ++kki) {
      #pragma unroll
      for (int m = 0; m < 4; ++m) {
        const int row = wr * 64 + m * 16 + (lane & 15);
        const int cg  = ((kki << 2) + (lane >> 4)) ^ (row & 7);
        af[kki][m] = *(const bf16x8*)(As + row * 128 + cg * 16);
      }
      #pragma unroll
      for (int n = 0; n < 4; ++n) {
        const int row = wc * 64 + n * 16 + (lane & 15);
        const int cg  = ((kki << 2) + (lane >> 4)) ^ (row & 7);
        bf_[kki][n] = *(const bf16x8*)(Bs + row * 128 + cg * 16);
      }
    }
    #pragma unroll
    for (int kki = 0; kki < 2; ++kki)
      #pragma unroll
      for (int m = 0; m < 4; ++m)
        #pragma unroll
        for (int n = 0; n < 4; ++n)
          acc[m][n] = MFMA_BF16(af[kki][m], bf_[kki][n], acc[m][n]);

    __syncthreads();
  }

  const int row0 = blockIdx.x * 128 + wr * 64;
  const int col0 = ylocal * 128 + wc * 64;
  #pragma unroll
  for (int m = 0; m < 4; ++m) {
    #pragma unroll
    for (int n = 0; n < 4; ++n) {
      #pragma unroll
      for (int j = 0; j < 4; ++j) {
        const int gm = row0 + m * 16 + ((lane >> 4) << 2) + j;
        const int gn = col0 + n * 16 + (lane & 15);
        const float v = acc[m][n][j];
        if (mode == 0) {
          Qb[(size_t)gm * 2048 + gn] = f2bf(v);
        } else if (mode == 1) {
          Kb[(size_t)gm * 512 + gn] = f2bf(v);
        } else {
          const int bb = gm >> 11, t2 = gm & 2047;
          Vtb[(size_t)bb * 512 * 2048 + (size_t)gn * 2048 + t2] = f2bf(v);
        }
      }
    }
  }
}

// ---------------------------------------------------------------- GEMM  C = A * B^T
// (out-projection; unchanged T3 minimal 2-phase structure)
template<int WMODE>
__global__ __launch_bounds__(256, 2)
void gemm_bt(const ushort_t* __restrict__ A, const ushort_t* __restrict__ B,
             void* __restrict__ Cout, int M, int N, int K) {
  __shared__ bf16x8 smem_v[4096];            // 64 KB
  char* smem = (char*)smem_v;
  const int tid  = threadIdx.x;
  const int lane = tid & 63;
  const int wave = tid >> 6;
  const int wr = wave >> 1, wc = wave & 1;
  const ushort_t* Abase = A + (size_t)blockIdx.x * 128 * K;
  const ushort_t* Bbase = B + (size_t)blockIdx.y * 128 * K;

  f32x4 acc[4][4] = {};
  const int nk = K >> 6;

  #pragma unroll
  for (int it = 0; it < 4; ++it) {
    const int chunk = it * 4 + wave;
    const int r  = chunk * 8 + (lane >> 3);
    const int cg = (lane & 7) ^ (r & 7);
    gload_lds16(Abase + (size_t)r * K + cg * 8, smem + chunk * 1024);
    gload_lds16(Bbase + (size_t)r * K + cg * 8, smem + 16384 + chunk * 1024);
  }
  __syncthreads();

  for (int t = 0; t < nk; ++t) {
    if (t + 1 < nk) {
      char* dst = smem + ((t + 1) & 1) * 32768;
      const int k0 = (t + 1) * 64;
      #pragma unroll
      for (int it = 0; it < 4; ++it) {
        const int chunk = it * 4 + wave;
        const int r  = chunk * 8 + (lane >> 3);
        const int cg = (lane & 7) ^ (r & 7);
        gload_lds16(Abase + (size_t)r * K + k0 + cg * 8, dst + chunk * 1024);
        gload_lds16(Bbase + (size_t)r * K + k0 + cg * 8, dst + 16384 + chunk * 1024);
      }
    }

    char* As = smem + (t & 1) * 32768;
    char* Bs = As + 16384;
    bf16x8 af[2][4], bf_[2][4];
    #pragma unroll
    for (int kki = 0; kki < 2; ++kki) {
      #pragma unroll
      for (int m = 0; m < 4; ++m) {
        const int row = wr * 64 + m * 16 + (lane & 15);
        const int cg  = ((kki << 2) + (lane >> 4)) ^ (row & 7);
        af[kki][m] = *(const bf16x8*)(As + row * 128 + cg * 16);
      }
      #pragma unroll
      for (int n = 0; n < 4; ++n) {
        const int row = wc * 64 + n * 16 + (lane & 15);
        const int cg  = ((kki << 2) + (lane >> 4)) ^ (row & 7);
        bf_[kki][n] = *(const bf16x8*)(Bs + row * 128 + cg * 16);
      }
    }
    #pragma unroll
    for (int kki = 0; kki < 2; ++kki)
      #pragma unroll
      for (int m = 0; m < 4; ++m)
        #pragma unroll
        for (int n = 0; n < 4; ++n)
          acc[m][n] = MFMA_BF16(af[kki][m], bf_[kki][n], acc[m][n]);

    __syncthreads();
  }

  const int row0 = blockIdx.x * 128 + wr * 64;
  const int col0 = blockIdx.y * 128 + wc * 64;
  #pragma unroll
  for (int m = 0; m < 4; ++m) {
    #pragma unroll
    for (int n = 0; n < 4; ++n) {
      #pragma unroll
      for (int j = 0; j < 4; ++j) {
        const int gm = row0 + m * 16 + ((lane >> 4) << 2) + j;
        const int gn = col0 + n * 16 + (lane & 15);
        const float v = acc[m][n][j];
        if (WMODE == 0) {
          ((ushort_t*)Cout)[(size_t)gm * N + gn] = f2bf(v);
        } else if (WMODE == 1) {
          ((float*)Cout)[(size_t)gm * N + gn] = v;
        } else {
          const int bb = gm >> 11, t2 = gm & 2047;
          ((ushort_t*)Cout)[(size_t)bb * N * 2048 + (size_t)gn * 2048 + t2] = f2bf(v);
        }
      }
    }
  }
}

// ---------------------------------------------------------------- RoPE for K only
__global__ __launch_bounds__(256)
void rope_k_kernel(ushort_t* __restrict__ K) {
  const int idx = blockIdx.x * 256 + threadIdx.x;
  const int NK = 4096 * 4 * 32;
  if (idx >= NK) return;
  const int t = idx >> 7, r = idx & 127;
  const int h = r >> 5, i = r & 31;
  ushort_t* p = K + (size_t)t * 512 + h * 128;
  const float f  = powf(10000.0f, -(float)i / 31.0f);
  const float th = (float)h * f;
  float sn, cs;
  sincosf(th, &sn, &cs);
  const float x1 = bf2f(p[i]), x2 = bf2f(p[i + 64]);
  p[i]      = f2bf(x1 * cs + x2 * sn);
  p[i + 64] = f2bf(-x1 * sn + x2 * cs);
}

// ---------------------------------------------------------------- flash attention
// 4 waves x 32 q-rows, KVBLK=64, 32x32x16 MFMA, swapped QK^T, in-register
// softmax + permlane P-distribution (T12), defer-max (T13), fused Q-RoPE.
// Sync: T3 minimal 2-phase (one full-drain __syncthreads per tile).
// qt mapping: z=0 descending, z=1 ascending — co-resident block pairs
// (idx, idx+256) then sum to a constant 34 tiles (load balance fix).
__global__ __launch_bounds__(256, 2)
void attn_kernel(const ushort_t* __restrict__ Q, const ushort_t* __restrict__ K,
                 const ushort_t* __restrict__ Vt, ushort_t* __restrict__ AO) {
  __shared__ bf16x8 smem_v[4096];            // 64 KB: 2 x (16KB K + 16KB V^T)
  char* smem = (char*)smem_v;
  const int tid  = threadIdx.x;
  const int lane = tid & 63;
  const int wq   = tid >> 6;
  const int ql   = lane & 31;
  const int hi   = lane >> 5;
  const int h  = blockIdx.y;
  const int b  = blockIdx.z;
  const int qt = (b == 0) ? ((int)gridDim.x - 1 - (int)blockIdx.x)
                          : (int)blockIdx.x;           // balanced pairing
  const int kh = h >> 2;                     // N_REP = 4
  const int q0b = qt * 128;
  const int qmin_w = q0b + wq * 32;
  const int qmax_w = qmin_w + 31;
  const int qrow = qmin_w + ql;

  const ushort_t* Qp = Q  + (size_t)b * 2048 * 2048 + (size_t)h  * 128;
  const ushort_t* Kp = K  + (size_t)b * 2048 * 512  + (size_t)kh * 128;
  const ushort_t* Vp = Vt + (size_t)b * 512 * 2048  + (size_t)kh * 128 * 2048;

  const int ntiles = (qt + 1) * 2;

  // ---- stage tile 0 into buffer 0 (HBM latency hides under Q-load + RoPE)
  #pragma unroll
  for (int it = 0; it < 4; ++it) {
    const int ck = it * 4 + wq;
    const int rK = ck * 4 + (lane >> 4);
    const int gK = (lane & 15) ^ (rK & 7);
    gload_lds16(Kp + (size_t)rK * 512 + gK * 8, smem + ck * 1024);
    const int rV = ck * 8 + (lane >> 3);
    const int gV = (lane & 7) ^ (rV & 7);
    gload_lds16(Vp + (size_t)rV * 2048 + gV * 8, smem + 16384 + ck * 1024);
  }

  // ---- load Q fragments + fused head-indexed RoPE (pairs are lane-local)
  bf16x8 qf[8];
  #pragma unroll
  for (int ks = 0; ks < 8; ++ks)
    qf[ks] = *(const bf16x8*)(Qp + (size_t)qrow * 2048 + ks * 16 + hi * 8);
  #pragma unroll
  for (int ks = 0; ks < 2; ++ks) {
    union { bf16x8 v; ushort_t us[8]; } X1, X2;
    X1.v = qf[ks]; X2.v = qf[ks + 4];
    #pragma unroll
    for (int e = 0; e < 8; ++e) {
      const int i = ks * 16 + hi * 8 + e;
      const float f = __expf(-(float)i * (9.2103403720f / 31.0f));  // 10000^(-i/31)
      float sn, cs;
      sincosf((float)h * f, &sn, &cs);
      const float x1 = bf2f(X1.us[e]), x2 = bf2f(X2.us[e]);
      X1.us[e] = f2bf(x1 * cs + x2 * sn);
      X2.us[e] = f2bf(-x1 * sn + x2 * cs);
    }
    qf[ks] = X1.v; qf[ks + 4] = X2.v;
  }

  float m_ = -3.0e38f, l_ = 0.f;
  f32x16 oacc[4] = {};
  const float scale = 0.08838834764831845f;  // 1/sqrt(128)

  __syncthreads();                           // tile 0 landed (full drain)

  for (int ti = 0; ti < ntiles; ++ti) {
    const int kv0 = ti * 64;
    if (ti + 1 < ntiles) {                   // issue next-tile stage first
      const int nkv0 = kv0 + 64;
      char* dst = smem + ((ti + 1) & 1) * 32768;
      #pragma unroll
      for (int it = 0; it < 4; ++it) {
        const int ck = it * 4 + wq;
        const int rK = ck * 4 + (lane >> 4);
        const int gK = (lane & 15) ^ (rK & 7);
        gload_lds16(Kp + (size_t)(nkv0 + rK) * 512 + gK * 8, dst + ck * 1024);
        const int rV = ck * 8 + (lane >> 3);
        const int gV = (lane & 7) ^ (rV & 7);
        gload_lds16(Vp + (size_t)rV * 2048 + nkv0 + gV * 8, dst + 16384 + ck * 1024);
      }
    }

    char* Ks = smem + (ti & 1) * 32768;
    char* Vs = Ks + 16384;
    if (kv0 <= qmax_w) {                     // wave-uniform activity gate
      // ---- QK^T (swapped): lane holds S^T[key][q=ql]
      f32x16 sacc[2] = {};
      __builtin_amdgcn_s_setprio(1);
      #pragma unroll
      for (int kg = 0; kg < 2; ++kg) {
        const int key = kg * 32 + ql;
        #pragma unroll
        for (int ks = 0; ks < 8; ++ks) {
          const int g = ((ks << 1) + hi) ^ (key & 7);
          const bf16x8 kf = *(const bf16x8*)(Ks + key * 256 + g * 16);
          sacc[kg] = MFMA32_BF16(kf, qf[ks], sacc[kg]);
        }
      }
      __builtin_amdgcn_s_setprio(0);

      // ---- scale + causal mask
      const bool domask = (kv0 + 63 > qmin_w);
      #pragma unroll
      for (int kg = 0; kg < 2; ++kg)
        #pragma unroll
        for (int r = 0; r < 16; ++r) {
          float v = sacc[kg][r] * scale;
          if (domask) {
            const int keyg = kv0 + kg * 32 + (r & 3) + 8 * (r >> 2) + 4 * hi;
            if (keyg > qrow) v = -3.0e38f;
          }
          sacc[kg][r] = v;
        }

      // ---- online softmax (row lane-local; partner half has other 32 keys)
      float pm = sacc[0][0];
      #pragma unroll
      for (int kg = 0; kg < 2; ++kg)
        #pragma unroll
        for (int r = 0; r < 16; ++r) pm = fmaxf(pm, sacc[kg][r]);
      pm = fmaxf(pm, __shfl_xor(pm, 32));

      if (__any(pm > m_ + 8.0f)) {           // T13 defer-max
        const float mn = fmaxf(m_, pm);
        const float alpha = __expf(m_ - mn);
        m_ = mn;
        l_ *= alpha;
        #pragma unroll
        for (int r = 0; r < 16; ++r) {
          const float ar = __shfl(alpha, (r & 3) + 8 * (r >> 2) + 4 * hi);
          #pragma unroll
          for (int dg = 0; dg < 4; ++dg) oacc[dg][r] *= ar;
        }
      }

      float rs = 0.f;
      #pragma unroll
      for (int kg = 0; kg < 2; ++kg)
        #pragma unroll
        for (int r = 0; r < 16; ++r) {
          const float p = __expf(sacc[kg][r] - m_);
          sacc[kg][r] = p;
          rs += p;
        }
      rs += __shfl_xor(rs, 32);
      l_ += rs;

      // ---- P -> A-fragments via pack + permlane32_swap (T12)
      bf16x8 pa[4];
      #pragma unroll
      for (int ks = 0; ks < 4; ++ks) {
        const int kg = ks >> 1;
        const int base = 8 * (ks & 1);
        union { uint32_t w[4]; bf16x8 v; } U;
        #pragma unroll
        for (int j = 0; j < 2; ++j) {
          uint32_t a  = packbf(sacc[kg][base + 2 * j],     sacc[kg][base + 2 * j + 1]);
          uint32_t bb = packbf(sacc[kg][base + 4 + 2 * j], sacc[kg][base + 4 + 2 * j + 1]);
          asm volatile("v_permlane32_swap_b32 %0, %1" : "+v"(a), "+v"(bb));
          U.w[j] = a; U.w[2 + j] = bb;
        }
        pa[ks] = U.v;
      }

      // ---- O += P V
      __builtin_amdgcn_s_setprio(1);
      #pragma unroll
      for (int dg = 0; dg < 4; ++dg) {
        const int d = dg * 32 + ql;
        #pragma unroll
        for (int ks = 0; ks < 4; ++ks) {
          const int g = ((ks << 1) + hi) ^ (d & 7);
          const bf16x8 vf = *(const bf16x8*)(Vs + d * 128 + g * 16);
          oacc[dg] = MFMA32_BF16(pa[ks], vf, oacc[dg]);
        }
      }
      __builtin_amdgcn_s_setprio(0);
    }

    __syncthreads();   // drains: stage(ti+1) landed; all waves done with buf
  }

  // ---- epilogue: normalize, store bf16
  const float linv = 1.0f / l_;
  ushort_t* AOp = AO + (size_t)b * 2048 * 2048 + (size_t)h * 128;
  #pragma unroll
  for (int r = 0; r < 16; ++r) {
    const int cr = (r & 3) + 8 * (r >> 2) + 4 * hi;
    const float li = __shfl(linv, cr);
    const int row = q0b + wq * 32 + cr;
    #pragma unroll
    for (int dg = 0; dg < 4; ++dg)
      AOp[(size_t)row * 2048 + dg * 32 + ql] = f2bf(oacc[dg][r] * li);
  }
}

// ---------------------------------------------------------------- launch
extern "C" void kernel_launch(void* const* d_in, const int* in_sizes, int n_in,
                              void* d_out, int out_size, void* d_ws, size_t ws_size,
                              hipStream_t stream) {
  const float* x  = (const float*)d_in[0];
  const float* wq = (const float*)d_in[1];
  const float* wk = (const float*)d_in[2];
  const float* wv = (const float*)d_in[3];
  const float* wo = (const float*)d_in[4];
  float* out = (float*)d_out;
  char* ws = (char*)d_ws;

  ushort_t* xb  = (ushort_t*)(ws);               // x   bf16  4096x2048
  ushort_t* wqb = (ushort_t*)(ws + 16777216);    // wq  bf16  2048x2048
  ushort_t* wkb = (ushort_t*)(ws + 25165824);    // wk  bf16   512x2048
  ushort_t* wvb = (ushort_t*)(ws + 27262976);    // wv  bf16   512x2048
  ushort_t* wob = (ushort_t*)(ws + 29360128);    // wo  bf16  2048x2048
  ushort_t* Qb  = (ushort_t*)(ws + 37748736);    // Q   bf16  4096x2048 (pre-RoPE)
  ushort_t* Kb  = (ushort_t*)(ws + 54525952);    // K   bf16  4096x512  (post-RoPE)
  ushort_t* Vtb = (ushort_t*)(ws + 58720256);    // V^T bf16  [2][512][2048]
  ushort_t* AOb = (ushort_t*)(ws + 62914560);    // attn out bf16 4096x2048

  cvt_kernel<<<dim3(8192, 5), 256, 0, stream>>>(x, wq, wk, wv, wo,
                                                xb, wqb, wkb, wvb, wob);
  gemm_qkv<<<dim3(32, 24), 256, 0, stream>>>(xb, wqb, wkb, wvb, Qb, Kb, Vtb);
  rope_k_kernel<<<dim3(2048), 256, 0, stream>>>(Kb);
  attn_kernel<<<dim3(16, 16, 2), 256, 0, stream>>>(Qb, Kb, Vtb, AOb);
  gemm_bt<1><<<dim3(32, 16), 256, 0, stream>>>(AOb, wob, out, 4096, 2048, 2048);
}

// Round 6
// 189.925 us; speedup vs baseline: 1.7949x; 1.0936x over previous
//
#include <hip/hip_runtime.h>
#include <cstdint>
#include <cstddef>

typedef __attribute__((ext_vector_type(8))) short bf16x8;
typedef __attribute__((ext_vector_type(4))) float f32x4;
typedef __attribute__((ext_vector_type(16))) float f32x16;
typedef unsigned short ushort_t;

#define MFMA_BF16(a, b, c) __builtin_amdgcn_mfma_f32_16x16x32_bf16((a), (b), (c), 0, 0, 0)
#define MFMA32_BF16(a, b, c) __builtin_amdgcn_mfma_f32_32x32x16_bf16((a), (b), (c), 0, 0, 0)

__device__ __forceinline__ unsigned short f2bf(float f) {
  unsigned int u = __float_as_uint(f);
  u += 0x7fffu + ((u >> 16) & 1u);           // round-to-nearest-even
  return (unsigned short)(u >> 16);
}
__device__ __forceinline__ float bf2f(unsigned short h) {
  return __uint_as_float(((unsigned int)h) << 16);
}
// single-instruction 2^x (v_exp_f32 IS 2^x on CDNA)
__device__ __forceinline__ float exp2_fast(float x) {
  float r;
  asm("v_exp_f32 %0, %1" : "=v"(r) : "v"(x));
  return r;
}
// T12: packed f32x2 -> bf16x2 (lo = src0, hi = src1); no builtin on gfx950
__device__ __forceinline__ uint32_t cvtpk_bf16(float lo, float hi) {
  uint32_t r;
  asm("v_cvt_pk_bf16_f32 %0, %1, %2" : "=v"(r) : "v"(lo), "v"(hi));
  return r;
}

__device__ __forceinline__ void gload_lds16(const void* g, void* lds) {
  __builtin_amdgcn_global_load_lds(
      (const __attribute__((address_space(1))) void*)g,
      (__attribute__((address_space(3))) void*)lds, 16, 0, 0);
}

// ---------------------------------------------------------------- convert
__global__ __launch_bounds__(256)
void cvt_kernel(const float* __restrict__ x, const float* __restrict__ wq,
                const float* __restrict__ wk, const float* __restrict__ wv,
                const float* __restrict__ wo,
                ushort_t* __restrict__ xb, ushort_t* __restrict__ wqb,
                ushort_t* __restrict__ wkb, ushort_t* __restrict__ wvb,
                ushort_t* __restrict__ wob) {
  const float* src; ushort_t* dst; int n;
  switch (blockIdx.y) {
    case 0:  src = x;  dst = xb;  n = 8388608; break;
    case 1:  src = wq; dst = wqb; n = 4194304; break;
    case 2:  src = wk; dst = wkb; n = 1048576; break;
    case 3:  src = wv; dst = wvb; n = 1048576; break;
    default: src = wo; dst = wob; n = 4194304; break;
  }
  const int i = (int)(blockIdx.x * 256u + threadIdx.x) * 4;
  if (i >= n) return;
  const float4 v = *(const float4*)(src + i);
  union { unsigned short us[4]; unsigned long long u64; } pk;
  pk.us[0] = f2bf(v.x); pk.us[1] = f2bf(v.y);
  pk.us[2] = f2bf(v.z); pk.us[3] = f2bf(v.w);
  *(unsigned long long*)(dst + i) = pk.u64;
}

// ---------------------------------------------------------------- fused QKV GEMM
// blockIdx.y: 0..15 -> Q (N=2048), 16..19 -> K (N=512), 20..23 -> V^T (N=512).
// T3 minimal 2-phase, race-free drain sync (verified structure).
__global__ __launch_bounds__(256, 2)
void gemm_qkv(const ushort_t* __restrict__ A,
              const ushort_t* __restrict__ WQ, const ushort_t* __restrict__ WK,
              const ushort_t* __restrict__ WV,
              ushort_t* __restrict__ Qb, ushort_t* __restrict__ Kb,
              ushort_t* __restrict__ Vtb) {
  __shared__ bf16x8 smem_v[4096];            // 64 KB
  char* smem = (char*)smem_v;
  const int tid  = threadIdx.x;
  const int lane = tid & 63;
  const int wave = tid >> 6;
  const int wr = wave >> 1, wc = wave & 1;
  const int y = blockIdx.y;
  int mode, ylocal;
  const ushort_t* Bsel;
  if (y < 16)      { mode = 0; ylocal = y;      Bsel = WQ; }
  else if (y < 20) { mode = 1; ylocal = y - 16; Bsel = WK; }
  else             { mode = 2; ylocal = y - 20; Bsel = WV; }
  const ushort_t* Abase = A + (size_t)blockIdx.x * 128 * 2048;
  const ushort_t* Bbase = Bsel + (size_t)ylocal * 128 * 2048;

  f32x4 acc[4][4] = {};

  #pragma unroll
  for (int it = 0; it < 4; ++it) {
    const int chunk = it * 4 + wave;
    const int r  = chunk * 8 + (lane >> 3);
    const int cg = (lane & 7) ^ (r & 7);
    gload_lds16(Abase + (size_t)r * 2048 + cg * 8, smem + chunk * 1024);
    gload_lds16(Bbase + (size_t)r * 2048 + cg * 8, smem + 16384 + chunk * 1024);
  }
  __syncthreads();

  for (int t = 0; t < 32; ++t) {
    if (t + 1 < 32) {
      char* dst = smem + ((t + 1) & 1) * 32768;
      const int k0 = (t + 1) * 64;
      #pragma unroll
      for (int it = 0; it < 4; ++it) {
        const int chunk = it * 4 + wave;
        const int r  = chunk * 8 + (lane >> 3);
        const int cg = (lane & 7) ^ (r & 7);
        gload_lds16(Abase + (size_t)r * 2048 + k0 + cg * 8, dst + chunk * 1024);
        gload_lds16(Bbase + (size_t)r * 2048 + k0 + cg * 8, dst + 16384 + chunk * 1024);
      }
    }

    char* As = smem + (t & 1) * 32768;
    char* Bs = As + 16384;
    bf16x8 af[2][4], bf_[2][4];
    #pragma unroll
    for (int kki = 0; kki < 2; ++kki) {
      #pragma unroll
      for (int m = 0; m < 4; ++m) {
        const int row = wr * 64 + m * 16 + (lane & 15);
        const int cg  = ((kki << 2) + (lane >> 4)) ^ (row & 7);
        af[kki][m] = *(const bf16x8*)(As + row * 128 + cg * 16);
      }
      #pragma unroll
      for (int n = 0; n < 4; ++n) {
        const int row = wc * 64 + n * 16 + (lane & 15);
        const int cg  = ((kki << 2) + (lane >> 4)) ^ (row & 7);
        bf_[kki][n] = *(const bf16x8*)(Bs + row * 128 + cg * 16);
      }
    }
    #pragma unroll
    for (int kki = 0; kki < 2; ++kki)
      #pragma unroll
      for (int m = 0; m < 4; ++m)
        #pragma unroll
        for (int n = 0; n < 4; ++n)
          acc[m][n] = MFMA_BF16(af[kki][m], bf_[kki][n], acc[m][n]);

    __syncthreads();
  }

  const int row0 = blockIdx.x * 128 + wr * 64;
  const int col0 = ylocal * 128 + wc * 64;
  #pragma unroll
  for (int m = 0; m < 4; ++m) {
    #pragma unroll
    for (int n = 0; n < 4; ++n) {
      #pragma unroll
      for (int j = 0; j < 4; ++j) {
        const int gm = row0 + m * 16 + ((lane >> 4) << 2) + j;
        const int gn = col0 + n * 16 + (lane & 15);
        const float v = acc[m][n][j];
        if (mode == 0) {
          Qb[(size_t)gm * 2048 + gn] = f2bf(v);
        } else if (mode == 1) {
          Kb[(size_t)gm * 512 + gn] = f2bf(v);
        } else {
          const int bb = gm >> 11, t2 = gm & 2047;
          Vtb[(size_t)bb * 512 * 2048 + (size_t)gn * 2048 + t2] = f2bf(v);
        }
      }
    }
  }
}

// ---------------------------------------------------------------- GEMM  C = A * B^T
// (out-projection; T3 minimal 2-phase structure)
template<int WMODE>
__global__ __launch_bounds__(256, 2)
void gemm_bt(const ushort_t* __restrict__ A, const ushort_t* __restrict__ B,
             void* __restrict__ Cout, int M, int N, int K) {
  __shared__ bf16x8 smem_v[4096];            // 64 KB
  char* smem = (char*)smem_v;
  const int tid  = threadIdx.x;
  const int lane = tid & 63;
  const int wave = tid >> 6;
  const int wr = wave >> 1, wc = wave & 1;
  const ushort_t* Abase = A + (size_t)blockIdx.x * 128 * K;
  const ushort_t* Bbase = B + (size_t)blockIdx.y * 128 * K;

  f32x4 acc[4][4] = {};
  const int nk = K >> 6;

  #pragma unroll
  for (int it = 0; it < 4; ++it) {
    const int chunk = it * 4 + wave;
    const int r  = chunk * 8 + (lane >> 3);
    const int cg = (lane & 7) ^ (r & 7);
    gload_lds16(Abase + (size_t)r * K + cg * 8, smem + chunk * 1024);
    gload_lds16(Bbase + (size_t)r * K + cg * 8, smem + 16384 + chunk * 1024);
  }
  __syncthreads();

  for (int t = 0; t < nk; ++t) {
    if (t + 1 < nk) {
      char* dst = smem + ((t + 1) & 1) * 32768;
      const int k0 = (t + 1) * 64;
      #pragma unroll
      for (int it = 0; it < 4; ++it) {
        const int chunk = it * 4 + wave;
        const int r  = chunk * 8 + (lane >> 3);
        const int cg = (lane & 7) ^ (r & 7);
        gload_lds16(Abase + (size_t)r * K + k0 + cg * 8, dst + chunk * 1024);
        gload_lds16(Bbase + (size_t)r * K + k0 + cg * 8, dst + 16384 + chunk * 1024);
      }
    }

    char* As = smem + (t & 1) * 32768;
    char* Bs = As + 16384;
    bf16x8 af[2][4], bf_[2][4];
    #pragma unroll
    for (int kki = 0; kki < 2; ++kki) {
      #pragma unroll
      for (int m = 0; m < 4; ++m) {
        const int row = wr * 64 + m * 16 + (lane & 15);
        const int cg  = ((kki << 2) + (lane >> 4)) ^ (row & 7);
        af[kki][m] = *(const bf16x8*)(As + row * 128 + cg * 16);
      }
      #pragma unroll
      for (int n = 0; n < 4; ++n) {
        const int row = wc * 64 + n * 16 + (lane & 15);
        const int cg  = ((kki << 2) + (lane >> 4)) ^ (row & 7);
        bf_[kki][n] = *(const bf16x8*)(Bs + row * 128 + cg * 16);
      }
    }
    #pragma unroll
    for (int kki = 0; kki < 2; ++kki)
      #pragma unroll
      for (int m = 0; m < 4; ++m)
        #pragma unroll
        for (int n = 0; n < 4; ++n)
          acc[m][n] = MFMA_BF16(af[kki][m], bf_[kki][n], acc[m][n]);

    __syncthreads();
  }

  const int row0 = blockIdx.x * 128 + wr * 64;
  const int col0 = blockIdx.y * 128 + wc * 64;
  #pragma unroll
  for (int m = 0; m < 4; ++m) {
    #pragma unroll
    for (int n = 0; n < 4; ++n) {
      #pragma unroll
      for (int j = 0; j < 4; ++j) {
        const int gm = row0 + m * 16 + ((lane >> 4) << 2) + j;
        const int gn = col0 + n * 16 + (lane & 15);
        const float v = acc[m][n][j];
        if (WMODE == 0) {
          ((ushort_t*)Cout)[(size_t)gm * N + gn] = f2bf(v);
        } else if (WMODE == 1) {
          ((float*)Cout)[(size_t)gm * N + gn] = v;
        } else {
          const int bb = gm >> 11, t2 = gm & 2047;
          ((ushort_t*)Cout)[(size_t)bb * N * 2048 + (size_t)gn * 2048 + t2] = f2bf(v);
        }
      }
    }
  }
}

// ---------------------------------------------------------------- RoPE for K only
__global__ __launch_bounds__(256)
void rope_k_kernel(ushort_t* __restrict__ K) {
  const int idx = blockIdx.x * 256 + threadIdx.x;
  const int NK = 4096 * 4 * 32;
  if (idx >= NK) return;
  const int t = idx >> 7, r = idx & 127;
  const int h = r >> 5, i = r & 31;
  ushort_t* p = K + (size_t)t * 512 + h * 128;
  const float f  = powf(10000.0f, -(float)i / 31.0f);
  const float th = (float)h * f;
  float sn, cs;
  sincosf(th, &sn, &cs);
  const float x1 = bf2f(p[i]), x2 = bf2f(p[i + 64]);
  p[i]      = f2bf(x1 * cs + x2 * sn);
  p[i + 64] = f2bf(-x1 * sn + x2 * cs);
}

// ---------------------------------------------------------------- flash attention
// 4 waves x 32 q-rows, KVBLK=64, 32x32x16 MFMA, swapped QK^T.
// THIS ROUND: exp2-domain softmax (scale*log2e folded into Q in the RoPE
// prologue -> zero per-tile scale muls; v_exp_f32 is 2^x single-inst),
// v_cvt_pk_bf16_f32 P-pack (T12 proper), tree reductions for max & sum.
// Sync: T3 minimal 2-phase, one full-drain __syncthreads per tile (verified).
__global__ __launch_bounds__(256, 2)
void attn_kernel(const ushort_t* __restrict__ Q, const ushort_t* __restrict__ K,
                 const ushort_t* __restrict__ Vt, ushort_t* __restrict__ AO) {
  __shared__ bf16x8 smem_v[4096];            // 64 KB: 2 x (16KB K + 16KB V^T)
  char* smem = (char*)smem_v;
  const int tid  = threadIdx.x;
  const int lane = tid & 63;
  const int wq   = tid >> 6;
  const int ql   = lane & 31;
  const int hi   = lane >> 5;
  const int h  = blockIdx.y;
  const int b  = blockIdx.z;
  const int qt = (b == 0) ? ((int)gridDim.x - 1 - (int)blockIdx.x)
                          : (int)blockIdx.x;           // balanced pairing
  const int kh = h >> 2;                     // N_REP = 4
  const int q0b = qt * 128;
  const int qmin_w = q0b + wq * 32;
  const int qmax_w = qmin_w + 31;
  const int qrow = qmin_w + ql;

  const ushort_t* Qp = Q  + (size_t)b * 2048 * 2048 + (size_t)h  * 128;
  const ushort_t* Kp = K  + (size_t)b * 2048 * 512  + (size_t)kh * 128;
  const ushort_t* Vp = Vt + (size_t)b * 512 * 2048  + (size_t)kh * 128 * 2048;

  const int ntiles = (qt + 1) * 2;

  // ---- stage tile 0 into buffer 0 (HBM latency hides under Q-load + RoPE)
  #pragma unroll
  for (int it = 0; it < 4; ++it) {
    const int ck = it * 4 + wq;
    const int rK = ck * 4 + (lane >> 4);
    const int gK = (lane & 15) ^ (rK & 7);
    gload_lds16(Kp + (size_t)rK * 512 + gK * 8, smem + ck * 1024);
    const int rV = ck * 8 + (lane >> 3);
    const int gV = (lane & 7) ^ (rV & 7);
    gload_lds16(Vp + (size_t)rV * 2048 + gV * 8, smem + 16384 + ck * 1024);
  }

  // ---- load Q fragments + fused head-indexed RoPE, with scale*log2e folded
  //      in f32 BEFORE the single bf16 rounding (same rounding count as before)
  const float SCL = 0.08838834764831845f * 1.4426950408889634f;
  bf16x8 qf[8];
  #pragma unroll
  for (int ks = 0; ks < 8; ++ks)
    qf[ks] = *(const bf16x8*)(Qp + (size_t)qrow * 2048 + ks * 16 + hi * 8);
  #pragma unroll
  for (int ks = 0; ks < 2; ++ks) {           // rotated pairs: cols [0,32)+[64,96)
    union { bf16x8 v; ushort_t us[8]; } X1, X2;
    X1.v = qf[ks]; X2.v = qf[ks + 4];
    #pragma unroll
    for (int e = 0; e < 8; ++e) {
      const int i = ks * 16 + hi * 8 + e;
      const float f = __expf(-(float)i * (9.2103403720f / 31.0f));  // 10000^(-i/31)
      float sn, cs;
      sincosf((float)h * f, &sn, &cs);
      const float x1 = bf2f(X1.us[e]), x2 = bf2f(X2.us[e]);
      X1.us[e] = f2bf((x1 * cs + x2 * sn) * SCL);
      X2.us[e] = f2bf((-x1 * sn + x2 * cs) * SCL);
    }
    qf[ks] = X1.v; qf[ks + 4] = X2.v;
  }
  #pragma unroll
  for (int ks = 2; ks < 4; ++ks) {           // unrotated: cols [32,64)+[96,128)
    union { bf16x8 v; ushort_t us[8]; } X1, X2;
    X1.v = qf[ks]; X2.v = qf[ks + 4];
    #pragma unroll
    for (int e = 0; e < 8; ++e) {
      X1.us[e] = f2bf(bf2f(X1.us[e]) * SCL);
      X2.us[e] = f2bf(bf2f(X2.us[e]) * SCL);
    }
    qf[ks] = X1.v; qf[ks + 4] = X2.v;
  }

  float m_ = -3.0e38f, l_ = 0.f;
  f32x16 oacc[4] = {};

  __syncthreads();                           // tile 0 landed (full drain)

  for (int ti = 0; ti < ntiles; ++ti) {
    const int kv0 = ti * 64;
    if (ti + 1 < ntiles) {                   // issue next-tile stage first
      const int nkv0 = kv0 + 64;
      char* dst = smem + ((ti + 1) & 1) * 32768;
      #pragma unroll
      for (int it = 0; it < 4; ++it) {
        const int ck = it * 4 + wq;
        const int rK = ck * 4 + (lane >> 4);
        const int gK = (lane & 15) ^ (rK & 7);
        gload_lds16(Kp + (size_t)(nkv0 + rK) * 512 + gK * 8, dst + ck * 1024);
        const int rV = ck * 8 + (lane >> 3);
        const int gV = (lane & 7) ^ (rV & 7);
        gload_lds16(Vp + (size_t)rV * 2048 + nkv0 + gV * 8, dst + 16384 + ck * 1024);
      }
    }

    char* Ks = smem + (ti & 1) * 32768;
    char* Vs = Ks + 16384;
    if (kv0 <= qmax_w) {                     // wave-uniform activity gate
      // ---- QK^T (swapped): lane holds S^T[key][q=ql], pre-scaled (log2 domain)
      f32x16 sacc[2] = {};
      __builtin_amdgcn_s_setprio(1);
      #pragma unroll
      for (int kg = 0; kg < 2; ++kg) {
        const int key = kg * 32 + ql;
        #pragma unroll
        for (int ks = 0; ks < 8; ++ks) {
          const int g = ((ks << 1) + hi) ^ (key & 7);
          const bf16x8 kf = *(const bf16x8*)(Ks + key * 256 + g * 16);
          sacc[kg] = MFMA32_BF16(kf, qf[ks], sacc[kg]);
        }
      }
      __builtin_amdgcn_s_setprio(0);

      // ---- causal mask (diagonal tiles only; no scale pass needed)
      if (kv0 + 63 > qmin_w) {
        #pragma unroll
        for (int kg = 0; kg < 2; ++kg)
          #pragma unroll
          for (int r = 0; r < 16; ++r) {
            const int keyg = kv0 + kg * 32 + (r & 3) + 8 * (r >> 2) + 4 * hi;
            if (keyg > qrow) sacc[kg][r] = -3.0e38f;
          }
      }

      // ---- online softmax, log2 domain (T13 defer-max, THR = 8*log2e ~ 11)
      float mx[8];
      #pragma unroll
      for (int i = 0; i < 8; ++i) {          // depth-3 tree over 32 values
        const int kg = i >> 2, base = (i & 3) * 4;
        mx[i] = fmaxf(fmaxf(sacc[kg][base], sacc[kg][base + 1]),
                      fmaxf(sacc[kg][base + 2], sacc[kg][base + 3]));
      }
      float pm = fmaxf(fmaxf(fmaxf(mx[0], mx[1]), fmaxf(mx[2], mx[3])),
                       fmaxf(fmaxf(mx[4], mx[5]), fmaxf(mx[6], mx[7])));
      pm = fmaxf(pm, __shfl_xor(pm, 32));

      if (__any(pm > m_ + 11.0f)) {
        const float mn = fmaxf(m_, pm);
        const float alpha = exp2_fast(m_ - mn);
        m_ = mn;
        l_ *= alpha;
        #pragma unroll
        for (int r = 0; r < 16; ++r) {
          const float ar = __shfl(alpha, (r & 3) + 8 * (r >> 2) + 4 * hi);
          #pragma unroll
          for (int dg = 0; dg < 4; ++dg) oacc[dg][r] *= ar;
        }
      }

      float rs0 = 0.f, rs1 = 0.f, rs2 = 0.f, rs3 = 0.f;   // 4 parallel chains
      #pragma unroll
      for (int kg = 0; kg < 2; ++kg)
        #pragma unroll
        for (int r = 0; r < 16; r += 4) {
          const float p0 = exp2_fast(sacc[kg][r]     - m_);
          const float p1 = exp2_fast(sacc[kg][r + 1] - m_);
          const float p2 = exp2_fast(sacc[kg][r + 2] - m_);
          const float p3 = exp2_fast(sacc[kg][r + 3] - m_);
          sacc[kg][r] = p0; sacc[kg][r + 1] = p1;
          sacc[kg][r + 2] = p2; sacc[kg][r + 3] = p3;
          rs0 += p0; rs1 += p1; rs2 += p2; rs3 += p3;
        }
      float rs = (rs0 + rs1) + (rs2 + rs3);
      rs += __shfl_xor(rs, 32);
      l_ += rs;

      // ---- P -> A-fragments via v_cvt_pk_bf16_f32 + permlane32_swap (T12)
      bf16x8 pa[4];
      #pragma unroll
      for (int ks = 0; ks < 4; ++ks) {
        const int kg = ks >> 1;
        const int base = 8 * (ks & 1);
        union { uint32_t w[4]; bf16x8 v; } U;
        #pragma unroll
        for (int j = 0; j < 2; ++j) {
          uint32_t a  = cvtpk_bf16(sacc[kg][base + 2 * j],     sacc[kg][base + 2 * j + 1]);
          uint32_t bb = cvtpk_bf16(sacc[kg][base + 4 + 2 * j], sacc[kg][base + 4 + 2 * j + 1]);
          asm volatile("v_permlane32_swap_b32 %0, %1" : "+v"(a), "+v"(bb));
          U.w[j] = a; U.w[2 + j] = bb;
        }
        pa[ks] = U.v;
      }

      // ---- O += P V
      __builtin_amdgcn_s_setprio(1);
      #pragma unroll
      for (int dg = 0; dg < 4; ++dg) {
        const int d = dg * 32 + ql;
        #pragma unroll
        for (int ks = 0; ks < 4; ++ks) {
          const int g = ((ks << 1) + hi) ^ (d & 7);
          const bf16x8 vf = *(const bf16x8*)(Vs + d * 128 + g * 16);
          oacc[dg] = MFMA32_BF16(pa[ks], vf, oacc[dg]);
        }
      }
      __builtin_amdgcn_s_setprio(0);
    }

    __syncthreads();   // drains: stage(ti+1) landed; all waves done with buf
  }

  // ---- epilogue: normalize, store bf16
  const float linv = 1.0f / l_;
  ushort_t* AOp = AO + (size_t)b * 2048 * 2048 + (size_t)h * 128;
  #pragma unroll
  for (int r = 0; r < 16; ++r) {
    const int cr = (r & 3) + 8 * (r >> 2) + 4 * hi;
    const float li = __shfl(linv, cr);
    const int row = q0b + wq * 32 + cr;
    #pragma unroll
    for (int dg = 0; dg < 4; ++dg)
      AOp[(size_t)row * 2048 + dg * 32 + ql] = f2bf(oacc[dg][r] * li);
  }
}

// ---------------------------------------------------------------- launch
extern "C" void kernel_launch(void* const* d_in, const int* in_sizes, int n_in,
                              void* d_out, int out_size, void* d_ws, size_t ws_size,
                              hipStream_t stream) {
  const float* x  = (const float*)d_in[0];
  const float* wq = (const float*)d_in[1];
  const float* wk = (const float*)d_in[2];
  const float* wv = (const float*)d_in[3];
  const float* wo = (const float*)d_in[4];
  float* out = (float*)d_out;
  char* ws = (char*)d_ws;

  ushort_t* xb  = (ushort_t*)(ws);               // x   bf16  4096x2048
  ushort_t* wqb = (ushort_t*)(ws + 16777216);    // wq  bf16  2048x2048
  ushort_t* wkb = (ushort_t*)(ws + 25165824);    // wk  bf16   512x2048
  ushort_t* wvb = (ushort_t*)(ws + 27262976);    // wv  bf16   512x2048
  ushort_t* wob = (ushort_t*)(ws + 29360128);    // wo  bf16  2048x2048
  ushort_t* Qb  = (ushort_t*)(ws + 37748736);    // Q   bf16  4096x2048 (pre-RoPE)
  ushort_t* Kb  = (ushort_t*)(ws + 54525952);    // K   bf16  4096x512  (post-RoPE)
  ushort_t* Vtb = (ushort_t*)(ws + 58720256);    // V^T bf16  [2][512][2048]
  ushort_t* AOb = (ushort_t*)(ws + 62914560);    // attn out bf16 4096x2048

  cvt_kernel<<<dim3(8192, 5), 256, 0, stream>>>(x, wq, wk, wv, wo,
                                                xb, wqb, wkb, wvb, wob);
  gemm_qkv<<<dim3(32, 24), 256, 0, stream>>>(xb, wqb, wkb, wvb, Qb, Kb, Vtb);
  rope_k_kernel<<<dim3(2048), 256, 0, stream>>>(Kb);
  attn_kernel<<<dim3(16, 16, 2), 256, 0, stream>>>(Qb, Kb, Vtb, AOb);
  gemm_bt<1><<<dim3(32, 16), 256, 0, stream>>>(AOb, wob, out, 4096, 2048, 2048);
}